// Round 2
// baseline (3037.690 us; speedup 1.0000x reference)
//
#include <hip/hip_runtime.h>
#include <hip/hip_bf16.h>
#include <math.h>

#define MQ      1024
#define NTRAIN  200000
#define NPAD    200064          // 1563 * 128
#define NTILES  1563
#define KDIM    768
#define NCLS    1000
#define CAP     1024
#define DELTA   12.0f
#define KSEL    32
#define TINV    (1.0f/0.07f)

typedef short s16x8 __attribute__((ext_vector_type(8)));
typedef float f32x4 __attribute__((ext_vector_type(4)));

__device__ __forceinline__ unsigned encf(float x){
    unsigned u = __float_as_uint(x);
    return (u & 0x80000000u) ? ~u : (u | 0x80000000u);
}
__device__ __forceinline__ float decf(unsigned e){
    unsigned u = (e & 0x80000000u) ? (e & 0x7FFFFFFFu) : ~e;
    return __uint_as_float(u);
}
__device__ __forceinline__ ushort cvt_bf16(float x){
    unsigned u = __float_as_uint(x);
    u += 0x7FFFu + ((u >> 16) & 1u);   // round-to-nearest-even
    return (ushort)(u >> 16);
}
__device__ __forceinline__ void gload_lds16(const void* g, void* l){
    __builtin_amdgcn_global_load_lds(
        (const __attribute__((address_space(1))) unsigned int*)g,
        (__attribute__((address_space(3))) unsigned int*)l, 16, 0, 0);
}

__global__ void init_kernel(unsigned* rowMaxBits, int* counts){
    int i = blockIdx.x * blockDim.x + threadIdx.x;
    if (i < MQ){ rowMaxBits[i] = 0u; counts[i] = 0; }
}

// fp32 -> bf16 conversion of A (1024 rows) and B (200000 rows, padded to 200064
// with zeros). 8 elems/thread, grid-stride.
__launch_bounds__(256)
__global__ void convert_kernel(const float* __restrict__ Aq,
                               const float* __restrict__ Bt,
                               ushort* __restrict__ Abf,
                               ushort* __restrict__ Bbf){
    const int total = (MQ + NPAD) * (KDIM / 8);   // 19,304,448 chunks
    for (int i = blockIdx.x * blockDim.x + threadIdx.x; i < total;
         i += gridDim.x * blockDim.x){
        int row = (unsigned)i / 96u;
        int c   = (unsigned)i % 96u;
        float4 v0 = make_float4(0.f,0.f,0.f,0.f), v1 = v0;
        ushort* dst;
        if (row < MQ){
            const float* src = Aq + (size_t)row * KDIM + c * 8;
            v0 = *reinterpret_cast<const float4*>(src);
            v1 = *reinterpret_cast<const float4*>(src + 4);
            dst = Abf + (size_t)row * KDIM + c * 8;
        } else {
            int br = row - MQ;
            dst = Bbf + (size_t)br * KDIM + c * 8;
            if (br < NTRAIN){
                const float* src = Bt + (size_t)br * KDIM + c * 8;
                v0 = *reinterpret_cast<const float4*>(src);
                v1 = *reinterpret_cast<const float4*>(src + 4);
            }
        }
        ushort4 h0, h1;
        h0.x = cvt_bf16(v0.x); h0.y = cvt_bf16(v0.y);
        h0.z = cvt_bf16(v0.z); h0.w = cvt_bf16(v0.w);
        h1.x = cvt_bf16(v1.x); h1.y = cvt_bf16(v1.y);
        h1.z = cvt_bf16(v1.z); h1.w = cvt_bf16(v1.w);
        *reinterpret_cast<ushort4*>(dst)     = h0;
        *reinterpret_cast<ushort4*>(dst + 4) = h1;
    }
}

// m97-structure GEMM: 128x128 tile, BK=64, global_load_lds width-16 staging of
// pre-converted bf16, fused running-max + candidate collect epilogue.
// 1D grid 12544, XCD-chunked: xcd = g&7 owns N-tiles [xcd*196, ...), the 8
// M-blocks of one N-tile are consecutive on the SAME XCD -> B panel L2 reuse.
__launch_bounds__(256)
__global__ void gemm_fast_kernel(const ushort* __restrict__ Abf,
                                 const ushort* __restrict__ Bbf,
                                 unsigned* __restrict__ rowMaxBits,
                                 int* __restrict__ counts,
                                 int* __restrict__ cands){
    const int g   = blockIdx.x;
    const int xcd = g & 7;
    const int l   = g >> 3;
    const int nt  = xcd * 196 + (l >> 3);
    if (nt >= NTILES) return;
    const int m0 = (l & 7) * 128;
    const int n0 = nt * 128;
    const int tid  = threadIdx.x;
    const int lane = tid & 63;
    const int wave = tid >> 6;
    const int wm = (wave >> 1) * 64;
    const int wn = (wave & 1) * 64;
    const int fr = lane & 15;
    const int fg = lane >> 4;

    __shared__ union {
        struct { ushort As[128 * 64]; ushort Bs[128 * 64]; } s;  // 32 KB
        float Csh[64][129];                                       // 33 KB
    } sm;

    f32x4 acc[4][4];
    #pragma unroll
    for (int i = 0; i < 4; ++i)
        #pragma unroll
        for (int j = 0; j < 4; ++j)
            acc[i][j] = (f32x4){0.f, 0.f, 0.f, 0.f};

    for (int kt = 0; kt < KDIM / 64; ++kt){
        const int k0 = kt * 64;
        __syncthreads();
        #pragma unroll
        for (int i = 0; i < 4; ++i){
            int idx = i * 256 + tid;          // 16B chunk id, 0..1023
            int r = idx >> 3, c = (idx & 7) << 3;
            gload_lds16(Abf + (size_t)(m0 + r) * KDIM + k0 + c, &sm.s.As[idx * 8]);
        }
        #pragma unroll
        for (int i = 0; i < 4; ++i){
            int idx = i * 256 + tid;
            int r = idx >> 3, c = (idx & 7) << 3;
            gload_lds16(Bbf + (size_t)(n0 + r) * KDIM + k0 + c, &sm.s.Bs[idx * 8]);
        }
        __syncthreads();
        #pragma unroll
        for (int kk = 0; kk < 2; ++kk){
            s16x8 af[4], bfv[4];
            #pragma unroll
            for (int i = 0; i < 4; ++i){
                af[i]  = *reinterpret_cast<const s16x8*>(&sm.s.As[(wm + i * 16 + fr) * 64 + kk * 32 + fg * 8]);
                bfv[i] = *reinterpret_cast<const s16x8*>(&sm.s.Bs[(wn + i * 16 + fr) * 64 + kk * 32 + fg * 8]);
            }
            #pragma unroll
            for (int i = 0; i < 4; ++i)
                #pragma unroll
                for (int j = 0; j < 4; ++j)
                    acc[i][j] = __builtin_amdgcn_mfma_f32_16x16x32_bf16(af[i], bfv[j], acc[i][j], 0, 0, 0);
        }
    }

    // epilogue: two 64-row half-tiles through LDS; per-row max + collect
    for (int half = 0; half < 2; ++half){
        __syncthreads();
        if ((wave >> 1) == half){
            #pragma unroll
            for (int i = 0; i < 4; ++i)
                #pragma unroll
                for (int j = 0; j < 4; ++j)
                    #pragma unroll
                    for (int q = 0; q < 4; ++q){
                        int rr = i * 16 + (lane >> 4) * 4 + q;
                        int cc = wn + j * 16 + (lane & 15);
                        sm.Csh[rr][cc] = acc[i][j][q];
                    }
        }
        __syncthreads();
        if (tid < 64){
            int grow = m0 + half * 64 + tid;
            float mx = -1e30f;
            #pragma unroll 4
            for (int c = 0; c < 128; ++c) mx = fmaxf(mx, sm.Csh[tid][c]);
            unsigned old = atomicMax(&rowMaxBits[grow], encf(mx));
            float gmax = fmaxf(mx, decf(old));
            float thr = gmax - DELTA;
            for (int c = 0; c < 128; ++c){
                int gcol = n0 + c;
                if (gcol < NTRAIN && sm.Csh[tid][c] >= thr){
                    int slot = atomicAdd(&counts[grow], 1);
                    if (slot < CAP) cands[(size_t)grow * CAP + slot] = gcol;
                }
            }
        }
    }
}

// ---- fallback GEMM (round-0 path, used only if ws too small) ----
__launch_bounds__(256)
__global__ void gemm_collect_kernel(const float* __restrict__ Aq,
                                    const float* __restrict__ Bt,
                                    unsigned* __restrict__ rowMaxBits,
                                    int* __restrict__ counts,
                                    int* __restrict__ cands){
    const int m0 = blockIdx.x * 128;
    const int n0 = blockIdx.y * 128;
    const int tid  = threadIdx.x;
    const int lane = tid & 63;
    const int wave = tid >> 6;
    const int wm = (wave >> 1) * 64;
    const int wn = (wave & 1) * 64;

    __shared__ union {
        struct { ushort As[128][32]; ushort Bs[128][32]; } s;
        float Csh[64][129];
    } sm;

    f32x4 acc[4][4];
    #pragma unroll
    for (int i = 0; i < 4; ++i)
        #pragma unroll
        for (int j = 0; j < 4; ++j)
            acc[i][j] = (f32x4){0.f, 0.f, 0.f, 0.f};

    const int fr = lane & 15;
    const int fg = lane >> 4;

    for (int kt = 0; kt < KDIM / 32; ++kt){
        const int k0 = kt * 32;
        __syncthreads();
        #pragma unroll
        for (int i = 0; i < 4; ++i){
            int f  = tid + i * 256;
            int r  = f >> 3;
            int kc = (f & 7) * 4;
            float4 av = *reinterpret_cast<const float4*>(Aq + (size_t)(m0 + r) * KDIM + k0 + kc);
            ushort4 ah; ah.x = cvt_bf16(av.x); ah.y = cvt_bf16(av.y);
            ah.z = cvt_bf16(av.z); ah.w = cvt_bf16(av.w);
            *reinterpret_cast<ushort4*>(&sm.s.As[r][kc]) = ah;
            int nr = n0 + r;
            float4 bv = make_float4(0.f, 0.f, 0.f, 0.f);
            if (nr < NTRAIN)
                bv = *reinterpret_cast<const float4*>(Bt + (size_t)nr * KDIM + k0 + kc);
            ushort4 bh; bh.x = cvt_bf16(bv.x); bh.y = cvt_bf16(bv.y);
            bh.z = cvt_bf16(bv.z); bh.w = cvt_bf16(bv.w);
            *reinterpret_cast<ushort4*>(&sm.s.Bs[r][kc]) = bh;
        }
        __syncthreads();
        s16x8 af[4], bfv[4];
        #pragma unroll
        for (int i = 0; i < 4; ++i){
            af[i]  = *reinterpret_cast<const s16x8*>(&sm.s.As[wm + i * 16 + fr][fg * 8]);
            bfv[i] = *reinterpret_cast<const s16x8*>(&sm.s.Bs[wn + i * 16 + fr][fg * 8]);
        }
        #pragma unroll
        for (int i = 0; i < 4; ++i)
            #pragma unroll
            for (int j = 0; j < 4; ++j)
                acc[i][j] = __builtin_amdgcn_mfma_f32_16x16x32_bf16(af[i], bfv[j], acc[i][j], 0, 0, 0);
    }

    for (int half = 0; half < 2; ++half){
        __syncthreads();
        if ((wave >> 1) == half){
            #pragma unroll
            for (int i = 0; i < 4; ++i)
                #pragma unroll
                for (int j = 0; j < 4; ++j)
                    #pragma unroll
                    for (int q = 0; q < 4; ++q){
                        int rr = i * 16 + (lane >> 4) * 4 + q;
                        int cc = wn + j * 16 + (lane & 15);
                        sm.Csh[rr][cc] = acc[i][j][q];
                    }
        }
        __syncthreads();
        if (tid < 64){
            int grow = m0 + half * 64 + tid;
            float mx = -1e30f;
            #pragma unroll 4
            for (int c = 0; c < 128; ++c) mx = fmaxf(mx, sm.Csh[tid][c]);
            unsigned old = atomicMax(&rowMaxBits[grow], encf(mx));
            float gmax = fmaxf(mx, decf(old));
            float thr = gmax - DELTA;
            for (int c = 0; c < 128; ++c){
                int gcol = n0 + c;
                if (gcol < NTRAIN && sm.Csh[tid][c] >= thr){
                    int slot = atomicAdd(&counts[grow], 1);
                    if (slot < CAP) cands[(size_t)grow * CAP + slot] = gcol;
                }
            }
        }
    }
}

// one block per query row: exact fp32 rescore, top-KSEL, softmax, output.
__launch_bounds__(256)
__global__ void rescore_output_kernel(const float* __restrict__ Aq,
                                      const float* __restrict__ Bt,
                                      const int* __restrict__ labels,
                                      const int* __restrict__ counts,
                                      const int* __restrict__ cands,
                                      float* __restrict__ out){
    const int row  = blockIdx.x;
    const int tid  = threadIdx.x;
    const int lane = tid & 63;
    const int wave = tid >> 6;

    __shared__ float q[KDIM];
    __shared__ float sv[CAP];
    __shared__ float rv[256];
    __shared__ int   ri[256];
    __shared__ float topS[KSEL];
    __shared__ int   topI[KSEL];
    __shared__ float cls[3][NCLS];

    for (int k = tid; k < KDIM; k += 256) q[k] = Aq[(size_t)row * KDIM + k];
    int m = counts[row]; if (m > CAP) m = CAP;
    __syncthreads();

    for (int c = wave; c < m; c += 4){
        int idx = cands[(size_t)row * CAP + c];
        const float* b = Bt + (size_t)idx * KDIM;
        float s = 0.f;
        #pragma unroll
        for (int u = 0; u < 12; ++u){
            int k = lane * 12 + u;
            s += q[k] * b[k];
        }
        #pragma unroll
        for (int off = 32; off; off >>= 1) s += __shfl_down(s, off);
        if (lane == 0) sv[c] = s;
    }
    __syncthreads();

    int msel = m < KSEL ? m : KSEL;
    for (int j = 0; j < msel; ++j){
        float bs = -1e30f; int bi = 0x7FFFFFFF;
        for (int c = tid; c < m; c += 256){
            float v = sv[c];
            if (v > bs){ bs = v; bi = c; }
        }
        rv[tid] = bs; ri[tid] = bi;
        __syncthreads();
        for (int st = 128; st; st >>= 1){
            if (tid < st){
                if (rv[tid + st] > rv[tid] ||
                    (rv[tid + st] == rv[tid] && ri[tid + st] < ri[tid])){
                    rv[tid] = rv[tid + st]; ri[tid] = ri[tid + st];
                }
            }
            __syncthreads();
        }
        if (tid == 0){
            topS[j] = rv[0];
            topI[j] = cands[(size_t)row * CAP + ri[0]];
            sv[ri[0]] = -1e30f;
        }
        __syncthreads();
    }

    for (int i = tid; i < 3 * NCLS; i += 256) (&cls[0][0])[i] = 0.f;
    __syncthreads();

    if (tid == 0){
        float s0 = topS[0];
        float e[KSEL];
        float Z = 0.f;
        for (int j = 0; j < msel; ++j){ e[j] = __expf((topS[j] - s0) * TINV); Z += e[j]; }
        float inv = 1.f / Z;
        for (int j = 0; j < msel; ++j){
            int lb = labels[topI[j]];
            float w = e[j] * inv;
            if (j < 10) cls[0][lb] += w;
            if (j < 50) cls[1][lb] += w;
            cls[2][lb] += w;
        }
    }
    __syncthreads();

    for (int c = tid; c < NCLS; c += 256){
        out[(size_t)row * NCLS + c]                         = cls[0][c];
        out[(size_t)MQ * NCLS + (size_t)row * NCLS + c]     = cls[1][c];
        out[(size_t)2 * MQ * NCLS + (size_t)row * NCLS + c] = cls[2][c];
    }
}

extern "C" void kernel_launch(void* const* d_in, const int* in_sizes, int n_in,
                              void* d_out, int out_size, void* d_ws, size_t ws_size,
                              hipStream_t stream){
    const float* Aq     = (const float*)d_in[0];
    const float* Bt     = (const float*)d_in[1];
    const int*   labels = (const int*)d_in[2];
    float* out = (float*)d_out;

    char* ws = (char*)d_ws;
    unsigned* rowMaxBits = (unsigned*)ws;                         // MQ u32
    int*      counts     = (int*)(ws + (size_t)MQ * 4);           // MQ i32
    int*      cands      = (int*)(ws + (size_t)MQ * 8);           // MQ*CAP i32
    ushort*   Abf        = (ushort*)(ws + (size_t)MQ * 8 + (size_t)MQ * CAP * 4);
    ushort*   Bbf        = Abf + (size_t)MQ * KDIM;

    const size_t need = (size_t)MQ * 8 + (size_t)MQ * CAP * 4
                      + (size_t)MQ * KDIM * 2 + (size_t)NPAD * KDIM * 2;

    hipLaunchKernelGGL(init_kernel, dim3(4), dim3(256), 0, stream, rowMaxBits, counts);

    if (ws_size >= need){
        hipLaunchKernelGGL(convert_kernel, dim3(2048), dim3(256), 0, stream,
                           Aq, Bt, Abf, Bbf);
        hipLaunchKernelGGL(gemm_fast_kernel, dim3(8 * 196 * 8), dim3(256), 0, stream,
                           Abf, Bbf, rowMaxBits, counts, cands);
    } else {
        hipLaunchKernelGGL(gemm_collect_kernel, dim3(8, (NTRAIN + 127) / 128), dim3(256), 0, stream,
                           Aq, Bt, rowMaxBits, counts, cands);
    }
    hipLaunchKernelGGL(rescore_output_kernel, dim3(MQ), dim3(256), 0, stream,
                       Aq, Bt, labels, counts, cands, out);
}

// Round 3
// 1230.626 us; speedup vs baseline: 2.4684x; 2.4684x over previous
//
#include <hip/hip_runtime.h>
#include <hip/hip_bf16.h>
#include <math.h>

#define MQ      1024
#define NTRAIN  200000
#define NPAD    200064          // 1563 * 128
#define NTILES  1563
#define KDIM    768
#define KT      12              // K tiles of 64
#define NCLS    1000
#define CAP     1024
#define DELTA   12.0f
#define KSEL    32
#define TINV    (1.0f/0.07f)

typedef short s16x8 __attribute__((ext_vector_type(8)));
typedef float f32x4 __attribute__((ext_vector_type(4)));

__device__ __forceinline__ unsigned encf(float x){
    unsigned u = __float_as_uint(x);
    return (u & 0x80000000u) ? ~u : (u | 0x80000000u);
}
__device__ __forceinline__ float decf(unsigned e){
    unsigned u = (e & 0x80000000u) ? (e & 0x7FFFFFFFu) : ~e;
    return __uint_as_float(u);
}
__device__ __forceinline__ ushort cvt_bf16(float x){
    unsigned u = __float_as_uint(x);
    u += 0x7FFFu + ((u >> 16) & 1u);   // round-to-nearest-even
    return (ushort)(u >> 16);
}
__device__ __forceinline__ void gload_lds16(const void* g, void* l){
    __builtin_amdgcn_global_load_lds(
        (const __attribute__((address_space(1))) unsigned int*)g,
        (__attribute__((address_space(3))) unsigned int*)l, 16, 0, 0);
}

__global__ void init_kernel(unsigned* rowMaxBits, int* counts){
    int i = blockIdx.x * blockDim.x + threadIdx.x;
    if (i < MQ){ rowMaxBits[i] = 0u; counts[i] = 0; }
}

// fp32 -> bf16 conversion into FRAGMENT-TILED layout.
// Tile = 128 rows x 64 k = 1024 chunks of 16B (8 bf16, consecutive k).
// chunk(r,k) = (((r>>4)*2 + (k>>5))*4 + ((k>>3)&3))*16 + (r&15)
// One block per tile; stage through LDS so global reads (float4, row-major)
// and global writes (linear 16B chunks) are both coalesced.
__launch_bounds__(256)
__global__ void convert_tile_kernel(const float* __restrict__ Aq,
                                    const float* __restrict__ Bt,
                                    ushort* __restrict__ Abf,
                                    ushort* __restrict__ Bbf){
    const int bid = blockIdx.x;            // (8 + 1563) * 12 tiles
    const int rt  = bid / KT;
    const int kt  = bid - rt * KT;
    const int tid = threadIdx.x;

    const float* src; ushort* dst; int rowBase, nRows;
    if (rt < 8){
        src = Aq; dst = Abf + (size_t)bid * 8192;
        rowBase = rt * 128; nRows = MQ;
    } else {
        src = Bt; dst = Bbf + (size_t)((rt - 8) * KT + kt) * 8192;
        rowBase = (rt - 8) * 128; nRows = NTRAIN;
    }

    __shared__ ushort tile[8192];   // 16 KB

    #pragma unroll
    for (int i = 0; i < 8; ++i){
        int idx = i * 256 + tid;           // float4 unit, 0..2047
        int r   = idx >> 4;                // 0..127
        int c4  = idx & 15;                // float4 col
        int grow = rowBase + r;
        float4 v = make_float4(0.f, 0.f, 0.f, 0.f);
        if (grow < nRows)
            v = *reinterpret_cast<const float4*>(src + (size_t)grow * KDIM + kt * 64 + c4 * 4);
        ushort4 h; h.x = cvt_bf16(v.x); h.y = cvt_bf16(v.y);
        h.z = cvt_bf16(v.z); h.w = cvt_bf16(v.w);
        int k = c4 * 4;
        int chunk = (((r >> 4) * 2 + (k >> 5)) * 4 + ((k >> 3) & 3)) * 16 + (r & 15);
        *reinterpret_cast<ushort4*>(&tile[chunk * 8 + (k & 7)]) = h;
    }
    __syncthreads();
    #pragma unroll
    for (int i = 0; i < 4; ++i){
        int c = i * 256 + tid;             // chunk id
        *reinterpret_cast<s16x8*>(dst + (size_t)c * 8) =
            *reinterpret_cast<const s16x8*>(&tile[c * 8]);
    }
}

// 128x128 tile, BK=64 GEMM on fragment-tiled bf16. global_load_lds staging is
// a linear 16KB copy; every fragment ds_read_b128 reads 1024 contiguous LDS
// bytes per wave -> zero bank conflicts. Fused max/collect epilogue.
// XCD-chunked 1D grid: the 8 M-blocks of one N-tile are consecutive on the
// same XCD -> B panel L2 reuse.
__launch_bounds__(256)
__global__ void gemm_fast_kernel(const ushort* __restrict__ Abf,
                                 const ushort* __restrict__ Bbf,
                                 unsigned* __restrict__ rowMaxBits,
                                 int* __restrict__ counts,
                                 int* __restrict__ cands){
    const int g   = blockIdx.x;
    const int xcd = g & 7;
    const int l   = g >> 3;
    const int nt  = xcd * 196 + (l >> 3);
    if (nt >= NTILES) return;
    const int m0 = (l & 7) * 128;
    const int n0 = nt * 128;
    const int tid  = threadIdx.x;
    const int lane = tid & 63;
    const int wave = tid >> 6;
    const int wm = (wave >> 1) * 64;
    const int wn = (wave & 1) * 64;
    const int fr = lane & 15;
    const int fg = lane >> 4;
    const int rgA = (wm >> 4);   // row-group base for A frags
    const int rgB = (wn >> 4);

    __shared__ union {
        struct { ushort As[8192]; ushort Bs[8192]; } s;  // 32 KB
        float Csh[64][129];                               // 33 KB
    } sm;

    const ushort* Atile = Abf + (size_t)(m0 >> 7) * KT * 8192;
    const ushort* Btile = Bbf + (size_t)nt * KT * 8192;

    f32x4 acc[4][4];
    #pragma unroll
    for (int i = 0; i < 4; ++i)
        #pragma unroll
        for (int j = 0; j < 4; ++j)
            acc[i][j] = (f32x4){0.f, 0.f, 0.f, 0.f};

    for (int kt = 0; kt < KT; ++kt){
        __syncthreads();
        #pragma unroll
        for (int i = 0; i < 4; ++i){
            int c = i * 256 + tid;
            gload_lds16(Atile + (size_t)kt * 8192 + c * 8, &sm.s.As[c * 8]);
        }
        #pragma unroll
        for (int i = 0; i < 4; ++i){
            int c = i * 256 + tid;
            gload_lds16(Btile + (size_t)kt * 8192 + c * 8, &sm.s.Bs[c * 8]);
        }
        __syncthreads();
        #pragma unroll
        for (int kk = 0; kk < 2; ++kk){
            s16x8 af[4], bfv[4];
            #pragma unroll
            for (int i = 0; i < 4; ++i){
                int ca = (((rgA + i) * 2 + kk) * 4 + fg) * 16 + fr;
                int cb = (((rgB + i) * 2 + kk) * 4 + fg) * 16 + fr;
                af[i]  = *reinterpret_cast<const s16x8*>(&sm.s.As[ca * 8]);
                bfv[i] = *reinterpret_cast<const s16x8*>(&sm.s.Bs[cb * 8]);
            }
            #pragma unroll
            for (int i = 0; i < 4; ++i)
                #pragma unroll
                for (int j = 0; j < 4; ++j)
                    acc[i][j] = __builtin_amdgcn_mfma_f32_16x16x32_bf16(af[i], bfv[j], acc[i][j], 0, 0, 0);
        }
    }

    // epilogue: two 64-row half-tiles through LDS; per-row max + collect
    for (int half = 0; half < 2; ++half){
        __syncthreads();
        if ((wave >> 1) == half){
            #pragma unroll
            for (int i = 0; i < 4; ++i)
                #pragma unroll
                for (int j = 0; j < 4; ++j)
                    #pragma unroll
                    for (int q = 0; q < 4; ++q){
                        int rr = i * 16 + (lane >> 4) * 4 + q;
                        int cc = wn + j * 16 + (lane & 15);
                        sm.Csh[rr][cc] = acc[i][j][q];
                    }
        }
        __syncthreads();
        if (tid < 64){
            int grow = m0 + half * 64 + tid;
            float mx = -1e30f;
            #pragma unroll 4
            for (int c = 0; c < 128; ++c) mx = fmaxf(mx, sm.Csh[tid][c]);
            unsigned old = atomicMax(&rowMaxBits[grow], encf(mx));
            float gmax = fmaxf(mx, decf(old));
            float thr = gmax - DELTA;
            for (int c = 0; c < 128; ++c){
                int gcol = n0 + c;
                if (gcol < NTRAIN && sm.Csh[tid][c] >= thr){
                    int slot = atomicAdd(&counts[grow], 1);
                    if (slot < CAP) cands[(size_t)grow * CAP + slot] = gcol;
                }
            }
        }
    }
}

// ---- fallback GEMM (round-0 path, used only if ws too small) ----
__launch_bounds__(256)
__global__ void gemm_collect_kernel(const float* __restrict__ Aq,
                                    const float* __restrict__ Bt,
                                    unsigned* __restrict__ rowMaxBits,
                                    int* __restrict__ counts,
                                    int* __restrict__ cands){
    const int m0 = blockIdx.x * 128;
    const int n0 = blockIdx.y * 128;
    const int tid  = threadIdx.x;
    const int lane = tid & 63;
    const int wave = tid >> 6;
    const int wm = (wave >> 1) * 64;
    const int wn = (wave & 1) * 64;

    __shared__ union {
        struct { ushort As[128][32]; ushort Bs[128][32]; } s;
        float Csh[64][129];
    } sm;

    f32x4 acc[4][4];
    #pragma unroll
    for (int i = 0; i < 4; ++i)
        #pragma unroll
        for (int j = 0; j < 4; ++j)
            acc[i][j] = (f32x4){0.f, 0.f, 0.f, 0.f};

    const int fr = lane & 15;
    const int fg = lane >> 4;

    for (int kt = 0; kt < KDIM / 32; ++kt){
        const int k0 = kt * 32;
        __syncthreads();
        #pragma unroll
        for (int i = 0; i < 4; ++i){
            int f  = tid + i * 256;
            int r  = f >> 3;
            int kc = (f & 7) * 4;
            float4 av = *reinterpret_cast<const float4*>(Aq + (size_t)(m0 + r) * KDIM + k0 + kc);
            ushort4 ah; ah.x = cvt_bf16(av.x); ah.y = cvt_bf16(av.y);
            ah.z = cvt_bf16(av.z); ah.w = cvt_bf16(av.w);
            *reinterpret_cast<ushort4*>(&sm.s.As[r][kc]) = ah;
            int nr = n0 + r;
            float4 bv = make_float4(0.f, 0.f, 0.f, 0.f);
            if (nr < NTRAIN)
                bv = *reinterpret_cast<const float4*>(Bt + (size_t)nr * KDIM + k0 + kc);
            ushort4 bh; bh.x = cvt_bf16(bv.x); bh.y = cvt_bf16(bv.y);
            bh.z = cvt_bf16(bv.z); bh.w = cvt_bf16(bv.w);
            *reinterpret_cast<ushort4*>(&sm.s.Bs[nr - n0][kc]) = bh;
        }
        __syncthreads();
        s16x8 af[4], bfv[4];
        #pragma unroll
        for (int i = 0; i < 4; ++i){
            af[i]  = *reinterpret_cast<const s16x8*>(&sm.s.As[wm + i * 16 + fr][fg * 8]);
            bfv[i] = *reinterpret_cast<const s16x8*>(&sm.s.Bs[wn + i * 16 + fr][fg * 8]);
        }
        #pragma unroll
        for (int i = 0; i < 4; ++i)
            #pragma unroll
            for (int j = 0; j < 4; ++j)
                acc[i][j] = __builtin_amdgcn_mfma_f32_16x16x32_bf16(af[i], bfv[j], acc[i][j], 0, 0, 0);
    }

    for (int half = 0; half < 2; ++half){
        __syncthreads();
        if ((wave >> 1) == half){
            #pragma unroll
            for (int i = 0; i < 4; ++i)
                #pragma unroll
                for (int j = 0; j < 4; ++j)
                    #pragma unroll
                    for (int q = 0; q < 4; ++q){
                        int rr = i * 16 + (lane >> 4) * 4 + q;
                        int cc = wn + j * 16 + (lane & 15);
                        sm.Csh[rr][cc] = acc[i][j][q];
                    }
        }
        __syncthreads();
        if (tid < 64){
            int grow = m0 + half * 64 + tid;
            float mx = -1e30f;
            #pragma unroll 4
            for (int c = 0; c < 128; ++c) mx = fmaxf(mx, sm.Csh[tid][c]);
            unsigned old = atomicMax(&rowMaxBits[grow], encf(mx));
            float gmax = fmaxf(mx, decf(old));
            float thr = gmax - DELTA;
            for (int c = 0; c < 128; ++c){
                int gcol = n0 + c;
                if (gcol < NTRAIN && sm.Csh[tid][c] >= thr){
                    int slot = atomicAdd(&counts[grow], 1);
                    if (slot < CAP) cands[(size_t)grow * CAP + slot] = gcol;
                }
            }
        }
    }
}

// one block per query row: exact fp32 rescore, top-KSEL, softmax, output.
__launch_bounds__(256)
__global__ void rescore_output_kernel(const float* __restrict__ Aq,
                                      const float* __restrict__ Bt,
                                      const int* __restrict__ labels,
                                      const int* __restrict__ counts,
                                      const int* __restrict__ cands,
                                      float* __restrict__ out){
    const int row  = blockIdx.x;
    const int tid  = threadIdx.x;
    const int lane = tid & 63;
    const int wave = tid >> 6;

    __shared__ float q[KDIM];
    __shared__ float sv[CAP];
    __shared__ float rv[256];
    __shared__ int   ri[256];
    __shared__ float topS[KSEL];
    __shared__ int   topI[KSEL];
    __shared__ float cls[3][NCLS];

    for (int k = tid; k < KDIM; k += 256) q[k] = Aq[(size_t)row * KDIM + k];
    int m = counts[row]; if (m > CAP) m = CAP;
    __syncthreads();

    for (int c = wave; c < m; c += 4){
        int idx = cands[(size_t)row * CAP + c];
        const float* b = Bt + (size_t)idx * KDIM;
        float s = 0.f;
        #pragma unroll
        for (int u = 0; u < 12; ++u){
            int k = lane * 12 + u;
            s += q[k] * b[k];
        }
        #pragma unroll
        for (int off = 32; off; off >>= 1) s += __shfl_down(s, off);
        if (lane == 0) sv[c] = s;
    }
    __syncthreads();

    int msel = m < KSEL ? m : KSEL;
    for (int j = 0; j < msel; ++j){
        float bs = -1e30f; int bi = 0x7FFFFFFF;
        for (int c = tid; c < m; c += 256){
            float v = sv[c];
            if (v > bs){ bs = v; bi = c; }
        }
        rv[tid] = bs; ri[tid] = bi;
        __syncthreads();
        for (int st = 128; st; st >>= 1){
            if (tid < st){
                if (rv[tid + st] > rv[tid] ||
                    (rv[tid + st] == rv[tid] && ri[tid + st] < ri[tid])){
                    rv[tid] = rv[tid + st]; ri[tid] = ri[tid + st];
                }
            }
            __syncthreads();
        }
        if (tid == 0){
            topS[j] = rv[0];
            topI[j] = cands[(size_t)row * CAP + ri[0]];
            sv[ri[0]] = -1e30f;
        }
        __syncthreads();
    }

    for (int i = tid; i < 3 * NCLS; i += 256) (&cls[0][0])[i] = 0.f;
    __syncthreads();

    if (tid == 0){
        float s0 = topS[0];
        float e[KSEL];
        float Z = 0.f;
        for (int j = 0; j < msel; ++j){ e[j] = __expf((topS[j] - s0) * TINV); Z += e[j]; }
        float inv = 1.f / Z;
        for (int j = 0; j < msel; ++j){
            int lb = labels[topI[j]];
            float w = e[j] * inv;
            if (j < 10) cls[0][lb] += w;
            if (j < 50) cls[1][lb] += w;
            cls[2][lb] += w;
        }
    }
    __syncthreads();

    for (int c = tid; c < NCLS; c += 256){
        out[(size_t)row * NCLS + c]                         = cls[0][c];
        out[(size_t)MQ * NCLS + (size_t)row * NCLS + c]     = cls[1][c];
        out[(size_t)2 * MQ * NCLS + (size_t)row * NCLS + c] = cls[2][c];
    }
}

extern "C" void kernel_launch(void* const* d_in, const int* in_sizes, int n_in,
                              void* d_out, int out_size, void* d_ws, size_t ws_size,
                              hipStream_t stream){
    const float* Aq     = (const float*)d_in[0];
    const float* Bt     = (const float*)d_in[1];
    const int*   labels = (const int*)d_in[2];
    float* out = (float*)d_out;

    char* ws = (char*)d_ws;
    unsigned* rowMaxBits = (unsigned*)ws;                         // MQ u32
    int*      counts     = (int*)(ws + (size_t)MQ * 4);           // MQ i32
    int*      cands      = (int*)(ws + (size_t)MQ * 8);           // MQ*CAP i32
    ushort*   Abf        = (ushort*)(ws + (size_t)MQ * 8 + (size_t)MQ * CAP * 4);
    ushort*   Bbf        = Abf + (size_t)8 * KT * 8192;

    const size_t need = (size_t)MQ * 8 + (size_t)MQ * CAP * 4
                      + ((size_t)8 * KT * 8192 + (size_t)NTILES * KT * 8192) * 2;

    hipLaunchKernelGGL(init_kernel, dim3(4), dim3(256), 0, stream, rowMaxBits, counts);

    if (ws_size >= need){
        hipLaunchKernelGGL(convert_tile_kernel, dim3((8 + NTILES) * KT), dim3(256), 0, stream,
                           Aq, Bt, Abf, Bbf);
        hipLaunchKernelGGL(gemm_fast_kernel, dim3(8 * 196 * 8), dim3(256), 0, stream,
                           Abf, Bbf, rowMaxBits, counts, cands);
    } else {
        hipLaunchKernelGGL(gemm_collect_kernel, dim3(8, (NTRAIN + 127) / 128), dim3(256), 0, stream,
                           Aq, Bt, rowMaxBits, counts, cands);
    }
    hipLaunchKernelGGL(rescore_output_kernel, dim3(MQ), dim3(256), 0, stream,
                       Aq, Bt, labels, counts, cands, out);
}

// Round 4
// 1203.280 us; speedup vs baseline: 2.5245x; 1.0227x over previous
//
#include <hip/hip_runtime.h>
#include <hip/hip_bf16.h>
#include <math.h>

#define MQ      1024
#define NTRAIN  200000
#define NTILES  1563
#define KDIM    768
#define KT      12              // K tiles of 64
#define NCLS    1000
#define CAP     1024
#define DELTA   12.0f
#define KSEL    32
#define TINV    (1.0f/0.07f)

typedef short s16x8 __attribute__((ext_vector_type(8)));
typedef float f32x4 __attribute__((ext_vector_type(4)));

__device__ __forceinline__ unsigned encf(float x){
    unsigned u = __float_as_uint(x);
    return (u & 0x80000000u) ? ~u : (u | 0x80000000u);
}
__device__ __forceinline__ float decf(unsigned e){
    unsigned u = (e & 0x80000000u) ? (e & 0x7FFFFFFFu) : ~e;
    return __uint_as_float(u);
}
__device__ __forceinline__ ushort cvt_bf16(float x){
    unsigned u = __float_as_uint(x);
    u += 0x7FFFu + ((u >> 16) & 1u);   // round-to-nearest-even
    return (ushort)(u >> 16);
}
__device__ __forceinline__ void gload_lds16(const void* g, void* l){
    __builtin_amdgcn_global_load_lds(
        (const __attribute__((address_space(1))) unsigned int*)g,
        (__attribute__((address_space(3))) unsigned int*)l, 16, 0, 0);
}

__global__ void init_kernel(unsigned* rowMaxBits, int* counts){
    int i = blockIdx.x * blockDim.x + threadIdx.x;
    if (i < MQ){ rowMaxBits[i] = 0u; counts[i] = 0; }
}

// fp32 -> bf16 conversion into FRAGMENT-TILED layout.
// Tile = 128 rows x 64 k = 1024 chunks of 16B (8 bf16, consecutive k).
// chunk(r,k) = (((r>>4)*2 + (k>>5))*4 + ((k>>3)&3))*16 + (r&15)
__launch_bounds__(256)
__global__ void convert_tile_kernel(const float* __restrict__ Aq,
                                    const float* __restrict__ Bt,
                                    ushort* __restrict__ Abf,
                                    ushort* __restrict__ Bbf){
    const int bid = blockIdx.x;            // (8 + 1563) * 12 tiles
    const int rt  = bid / KT;
    const int kt  = bid - rt * KT;
    const int tid = threadIdx.x;

    const float* src; ushort* dst; int rowBase, nRows;
    if (rt < 8){
        src = Aq; dst = Abf + (size_t)bid * 8192;
        rowBase = rt * 128; nRows = MQ;
    } else {
        src = Bt; dst = Bbf + (size_t)((rt - 8) * KT + kt) * 8192;
        rowBase = (rt - 8) * 128; nRows = NTRAIN;
    }

    __shared__ ushort tile[8192];   // 16 KB

    #pragma unroll
    for (int i = 0; i < 8; ++i){
        int idx = i * 256 + tid;           // float4 unit, 0..2047
        int r   = idx >> 4;                // 0..127
        int c4  = idx & 15;                // float4 col
        int grow = rowBase + r;
        float4 v = make_float4(0.f, 0.f, 0.f, 0.f);
        if (grow < nRows)
            v = *reinterpret_cast<const float4*>(src + (size_t)grow * KDIM + kt * 64 + c4 * 4);
        ushort4 h; h.x = cvt_bf16(v.x); h.y = cvt_bf16(v.y);
        h.z = cvt_bf16(v.z); h.w = cvt_bf16(v.w);
        int k = c4 * 4;
        int chunk = (((r >> 4) * 2 + (k >> 5)) * 4 + ((k >> 3) & 3)) * 16 + (r & 15);
        *reinterpret_cast<ushort4*>(&tile[chunk * 8 + (k & 7)]) = h;
    }
    __syncthreads();
    #pragma unroll
    for (int i = 0; i < 4; ++i){
        int c = i * 256 + tid;             // chunk id
        *reinterpret_cast<s16x8*>(dst + (size_t)c * 8) =
            *reinterpret_cast<const s16x8*>(&tile[c * 8]);
    }
}

__device__ __forceinline__ void stage_tiles(const ushort* At, const ushort* Bt2,
                                            ushort* As, ushort* Bs, int tid){
    #pragma unroll
    for (int i = 0; i < 4; ++i){
        int c = i * 256 + tid;
        gload_lds16(At + (size_t)c * 8, As + (size_t)c * 8);
    }
    #pragma unroll
    for (int i = 0; i < 4; ++i){
        int c = i * 256 + tid;
        gload_lds16(Bt2 + (size_t)c * 8, Bs + (size_t)c * 8);
    }
}

// 128x128 tile, BK=64, DOUBLE-BUFFERED fragment-tiled bf16 GEMM.
// 2-phase schedule (T3 minimum): issue next tile's global_load_lds BEFORE
// current tile's ds_read+MFMA; the trailing __syncthreads (implicit vmcnt(0))
// lands AFTER compute, so the prefetch latency hides under the MFMA phase.
__launch_bounds__(256)
__global__ void gemm_fast_kernel(const ushort* __restrict__ Abf,
                                 const ushort* __restrict__ Bbf,
                                 unsigned* __restrict__ rowMaxBits,
                                 int* __restrict__ counts,
                                 int* __restrict__ cands){
    const int g   = blockIdx.x;
    const int xcd = g & 7;
    const int l   = g >> 3;
    const int nt  = xcd * 196 + (l >> 3);
    if (nt >= NTILES) return;
    const int m0 = (l & 7) * 128;
    const int n0 = nt * 128;
    const int tid  = threadIdx.x;
    const int lane = tid & 63;
    const int wave = tid >> 6;
    const int wm = (wave >> 1) * 64;
    const int wn = (wave & 1) * 64;
    const int fr = lane & 15;
    const int fg = lane >> 4;
    const int rgA = (wm >> 4);
    const int rgB = (wn >> 4);

    __shared__ union {
        ushort stg[2][16384];     // [buf][A:0..8191 | B:8192..16383]  64 KB
        float  Csh[64][129];      // 33 KB epilogue staging
    } sm;

    const ushort* Atile = Abf + (size_t)(m0 >> 7) * KT * 8192;
    const ushort* Btile = Bbf + (size_t)nt * KT * 8192;

    f32x4 acc[4][4];
    #pragma unroll
    for (int i = 0; i < 4; ++i)
        #pragma unroll
        for (int j = 0; j < 4; ++j)
            acc[i][j] = (f32x4){0.f, 0.f, 0.f, 0.f};

    // prologue: stage tile 0 into buffer 0
    stage_tiles(Atile, Btile, &sm.stg[0][0], &sm.stg[0][8192], tid);
    __syncthreads();   // implicit vmcnt(0) drain

    #pragma unroll
    for (int kt = 0; kt < KT; ++kt){
        const int cur = kt & 1;
        // prefetch next K-tile into the other buffer (flies during MFMA below)
        if (kt + 1 < KT)
            stage_tiles(Atile + (size_t)(kt + 1) * 8192,
                        Btile + (size_t)(kt + 1) * 8192,
                        &sm.stg[cur ^ 1][0], &sm.stg[cur ^ 1][8192], tid);
        const ushort* As = &sm.stg[cur][0];
        const ushort* Bs = &sm.stg[cur][8192];
        #pragma unroll
        for (int kk = 0; kk < 2; ++kk){
            s16x8 af[4], bfv[4];
            #pragma unroll
            for (int i = 0; i < 4; ++i){
                int ca = (((rgA + i) * 2 + kk) * 4 + fg) * 16 + fr;
                int cb = (((rgB + i) * 2 + kk) * 4 + fg) * 16 + fr;
                af[i]  = *reinterpret_cast<const s16x8*>(&As[ca * 8]);
                bfv[i] = *reinterpret_cast<const s16x8*>(&Bs[cb * 8]);
            }
            #pragma unroll
            for (int i = 0; i < 4; ++i)
                #pragma unroll
                for (int j = 0; j < 4; ++j)
                    acc[i][j] = __builtin_amdgcn_mfma_f32_16x16x32_bf16(af[i], bfv[j], acc[i][j], 0, 0, 0);
        }
        __syncthreads();   // drains prefetch vmcnt + protects cur buf reuse
    }

    // epilogue: two 64-row half-tiles through LDS; per-row max + collect
    for (int half = 0; half < 2; ++half){
        __syncthreads();
        if ((wave >> 1) == half){
            #pragma unroll
            for (int i = 0; i < 4; ++i)
                #pragma unroll
                for (int j = 0; j < 4; ++j)
                    #pragma unroll
                    for (int q = 0; q < 4; ++q){
                        int rr = i * 16 + (lane >> 4) * 4 + q;
                        int cc = wn + j * 16 + (lane & 15);
                        sm.Csh[rr][cc] = acc[i][j][q];
                    }
        }
        __syncthreads();
        if (tid < 64){
            int grow = m0 + half * 64 + tid;
            float mx = -1e30f;
            #pragma unroll 4
            for (int c = 0; c < 128; ++c) mx = fmaxf(mx, sm.Csh[tid][c]);
            unsigned old = atomicMax(&rowMaxBits[grow], encf(mx));
            float gmax = fmaxf(mx, decf(old));
            float thr = gmax - DELTA;
            for (int c = 0; c < 128; ++c){
                int gcol = n0 + c;
                if (gcol < NTRAIN && sm.Csh[tid][c] >= thr){
                    int slot = atomicAdd(&counts[grow], 1);
                    if (slot < CAP) cands[(size_t)grow * CAP + slot] = gcol;
                }
            }
        }
    }
}

// ---- fallback GEMM (round-0 path, used only if ws too small) ----
__launch_bounds__(256)
__global__ void gemm_collect_kernel(const float* __restrict__ Aq,
                                    const float* __restrict__ Bt,
                                    unsigned* __restrict__ rowMaxBits,
                                    int* __restrict__ counts,
                                    int* __restrict__ cands){
    const int m0 = blockIdx.x * 128;
    const int n0 = blockIdx.y * 128;
    const int tid  = threadIdx.x;
    const int lane = tid & 63;
    const int wave = tid >> 6;
    const int wm = (wave >> 1) * 64;
    const int wn = (wave & 1) * 64;

    __shared__ union {
        struct { ushort As[128][32]; ushort Bs[128][32]; } s;
        float Csh[64][129];
    } sm;

    f32x4 acc[4][4];
    #pragma unroll
    for (int i = 0; i < 4; ++i)
        #pragma unroll
        for (int j = 0; j < 4; ++j)
            acc[i][j] = (f32x4){0.f, 0.f, 0.f, 0.f};

    const int fr = lane & 15;
    const int fg = lane >> 4;

    for (int kt = 0; kt < KDIM / 32; ++kt){
        const int k0 = kt * 32;
        __syncthreads();
        #pragma unroll
        for (int i = 0; i < 4; ++i){
            int f  = tid + i * 256;
            int r  = f >> 3;
            int kc = (f & 7) * 4;
            float4 av = *reinterpret_cast<const float4*>(Aq + (size_t)(m0 + r) * KDIM + k0 + kc);
            ushort4 ah; ah.x = cvt_bf16(av.x); ah.y = cvt_bf16(av.y);
            ah.z = cvt_bf16(av.z); ah.w = cvt_bf16(av.w);
            *reinterpret_cast<ushort4*>(&sm.s.As[r][kc]) = ah;
            int nr = n0 + r;
            float4 bv = make_float4(0.f, 0.f, 0.f, 0.f);
            if (nr < NTRAIN)
                bv = *reinterpret_cast<const float4*>(Bt + (size_t)nr * KDIM + k0 + kc);
            ushort4 bh; bh.x = cvt_bf16(bv.x); bh.y = cvt_bf16(bv.y);
            bh.z = cvt_bf16(bv.z); bh.w = cvt_bf16(bv.w);
            *reinterpret_cast<ushort4*>(&sm.s.Bs[r][kc]) = bh;
        }
        __syncthreads();
        s16x8 af[4], bfv[4];
        #pragma unroll
        for (int i = 0; i < 4; ++i){
            af[i]  = *reinterpret_cast<const s16x8*>(&sm.s.As[wm + i * 16 + fr][fg * 8]);
            bfv[i] = *reinterpret_cast<const s16x8*>(&sm.s.Bs[wn + i * 16 + fr][fg * 8]);
        }
        #pragma unroll
        for (int i = 0; i < 4; ++i)
            #pragma unroll
            for (int j = 0; j < 4; ++j)
                acc[i][j] = __builtin_amdgcn_mfma_f32_16x16x32_bf16(af[i], bfv[j], acc[i][j], 0, 0, 0);
    }

    for (int half = 0; half < 2; ++half){
        __syncthreads();
        if ((wave >> 1) == half){
            #pragma unroll
            for (int i = 0; i < 4; ++i)
                #pragma unroll
                for (int j = 0; j < 4; ++j)
                    #pragma unroll
                    for (int q = 0; q < 4; ++q){
                        int rr = i * 16 + (lane >> 4) * 4 + q;
                        int cc = wn + j * 16 + (lane & 15);
                        sm.Csh[rr][cc] = acc[i][j][q];
                    }
        }
        __syncthreads();
        if (tid < 64){
            int grow = m0 + half * 64 + tid;
            float mx = -1e30f;
            #pragma unroll 4
            for (int c = 0; c < 128; ++c) mx = fmaxf(mx, sm.Csh[tid][c]);
            unsigned old = atomicMax(&rowMaxBits[grow], encf(mx));
            float gmax = fmaxf(mx, decf(old));
            float thr = gmax - DELTA;
            for (int c = 0; c < 128; ++c){
                int gcol = n0 + c;
                if (gcol < NTRAIN && sm.Csh[tid][c] >= thr){
                    int slot = atomicAdd(&counts[grow], 1);
                    if (slot < CAP) cands[(size_t)grow * CAP + slot] = gcol;
                }
            }
        }
    }
}

// one block per query row: exact fp32 rescore, top-KSEL, softmax, output.
__launch_bounds__(256)
__global__ void rescore_output_kernel(const float* __restrict__ Aq,
                                      const float* __restrict__ Bt,
                                      const int* __restrict__ labels,
                                      const int* __restrict__ counts,
                                      const int* __restrict__ cands,
                                      float* __restrict__ out){
    const int row  = blockIdx.x;
    const int tid  = threadIdx.x;
    const int lane = tid & 63;
    const int wave = tid >> 6;

    __shared__ float q[KDIM];
    __shared__ float sv[CAP];
    __shared__ float rv[256];
    __shared__ int   ri[256];
    __shared__ float topS[KSEL];
    __shared__ int   topI[KSEL];
    __shared__ float cls[3][NCLS];

    for (int k = tid; k < KDIM; k += 256) q[k] = Aq[(size_t)row * KDIM + k];
    int m = counts[row]; if (m > CAP) m = CAP;
    __syncthreads();

    for (int c = wave; c < m; c += 4){
        int idx = cands[(size_t)row * CAP + c];
        const float* b = Bt + (size_t)idx * KDIM;
        float s = 0.f;
        #pragma unroll
        for (int u = 0; u < 12; ++u){
            int k = lane * 12 + u;
            s += q[k] * b[k];
        }
        #pragma unroll
        for (int off = 32; off; off >>= 1) s += __shfl_down(s, off);
        if (lane == 0) sv[c] = s;
    }
    __syncthreads();

    int msel = m < KSEL ? m : KSEL;
    for (int j = 0; j < msel; ++j){
        float bs = -1e30f; int bi = 0x7FFFFFFF;
        for (int c = tid; c < m; c += 256){
            float v = sv[c];
            if (v > bs){ bs = v; bi = c; }
        }
        rv[tid] = bs; ri[tid] = bi;
        __syncthreads();
        for (int st = 128; st; st >>= 1){
            if (tid < st){
                if (rv[tid + st] > rv[tid] ||
                    (rv[tid + st] == rv[tid] && ri[tid + st] < ri[tid])){
                    rv[tid] = rv[tid + st]; ri[tid] = ri[tid + st];
                }
            }
            __syncthreads();
        }
        if (tid == 0){
            topS[j] = rv[0];
            topI[j] = cands[(size_t)row * CAP + ri[0]];
            sv[ri[0]] = -1e30f;
        }
        __syncthreads();
    }

    for (int i = tid; i < 3 * NCLS; i += 256) (&cls[0][0])[i] = 0.f;
    __syncthreads();

    if (tid == 0){
        float s0 = topS[0];
        float e[KSEL];
        float Z = 0.f;
        for (int j = 0; j < msel; ++j){ e[j] = __expf((topS[j] - s0) * TINV); Z += e[j]; }
        float inv = 1.f / Z;
        for (int j = 0; j < msel; ++j){
            int lb = labels[topI[j]];
            float w = e[j] * inv;
            if (j < 10) cls[0][lb] += w;
            if (j < 50) cls[1][lb] += w;
            cls[2][lb] += w;
        }
    }
    __syncthreads();

    for (int c = tid; c < NCLS; c += 256){
        out[(size_t)row * NCLS + c]                         = cls[0][c];
        out[(size_t)MQ * NCLS + (size_t)row * NCLS + c]     = cls[1][c];
        out[(size_t)2 * MQ * NCLS + (size_t)row * NCLS + c] = cls[2][c];
    }
}

extern "C" void kernel_launch(void* const* d_in, const int* in_sizes, int n_in,
                              void* d_out, int out_size, void* d_ws, size_t ws_size,
                              hipStream_t stream){
    const float* Aq     = (const float*)d_in[0];
    const float* Bt     = (const float*)d_in[1];
    const int*   labels = (const int*)d_in[2];
    float* out = (float*)d_out;

    char* ws = (char*)d_ws;
    unsigned* rowMaxBits = (unsigned*)ws;                         // MQ u32
    int*      counts     = (int*)(ws + (size_t)MQ * 4);           // MQ i32
    int*      cands      = (int*)(ws + (size_t)MQ * 8);           // MQ*CAP i32
    ushort*   Abf        = (ushort*)(ws + (size_t)MQ * 8 + (size_t)MQ * CAP * 4);
    ushort*   Bbf        = Abf + (size_t)8 * KT * 8192;

    const size_t need = (size_t)MQ * 8 + (size_t)MQ * CAP * 4
                      + ((size_t)8 * KT * 8192 + (size_t)NTILES * KT * 8192) * 2;

    hipLaunchKernelGGL(init_kernel, dim3(4), dim3(256), 0, stream, rowMaxBits, counts);

    if (ws_size >= need){
        hipLaunchKernelGGL(convert_tile_kernel, dim3((8 + NTILES) * KT), dim3(256), 0, stream,
                           Aq, Bt, Abf, Bbf);
        hipLaunchKernelGGL(gemm_fast_kernel, dim3(8 * 196 * 8), dim3(256), 0, stream,
                           Abf, Bbf, rowMaxBits, counts, cands);
    } else {
        hipLaunchKernelGGL(gemm_collect_kernel, dim3(8, (NTRAIN + 127) / 128), dim3(256), 0, stream,
                           Aq, Bt, rowMaxBits, counts, cands);
    }
    hipLaunchKernelGGL(rescore_output_kernel, dim3(MQ), dim3(256), 0, stream,
                       Aq, Bt, labels, counts, cands, out);
}

// Round 5
// 1094.545 us; speedup vs baseline: 2.7753x; 1.0993x over previous
//
#include <hip/hip_runtime.h>
#include <hip/hip_bf16.h>
#include <math.h>

#define MQ      1024
#define NTRAIN  200000
#define NTILES  1563
#define KDIM    768
#define KT      12              // K tiles of 64
#define NCLS    1000
#define CAP     1024
#define DELTA   12.0f
#define KSEL    32
#define TINV    (1.0f/0.07f)

typedef short s16x8 __attribute__((ext_vector_type(8)));
typedef float f32x4 __attribute__((ext_vector_type(4)));

__device__ __forceinline__ unsigned encf(float x){
    unsigned u = __float_as_uint(x);
    return (u & 0x80000000u) ? ~u : (u | 0x80000000u);
}
__device__ __forceinline__ float decf(unsigned e){
    unsigned u = (e & 0x80000000u) ? (e & 0x7FFFFFFFu) : ~e;
    return __uint_as_float(u);
}
__device__ __forceinline__ ushort cvt_bf16(float x){
    unsigned u = __float_as_uint(x);
    u += 0x7FFFu + ((u >> 16) & 1u);   // round-to-nearest-even
    return (ushort)(u >> 16);
}
__device__ __forceinline__ void gload_lds16(const void* g, void* l){
    __builtin_amdgcn_global_load_lds(
        (const __attribute__((address_space(1))) unsigned int*)g,
        (__attribute__((address_space(3))) unsigned int*)l, 16, 0, 0);
}

// counted-vmcnt wait + raw barrier (T4). memory clobber orders the
// gload_lds / ds_read memory ops; sched_barrier stops scheduler hoisting.
#define VMWAIT(N) asm volatile("s_waitcnt vmcnt(" #N ")" ::: "memory")
#define RBARRIER() do { __builtin_amdgcn_s_barrier(); \
                        __builtin_amdgcn_sched_barrier(0); } while (0)

__global__ void init_kernel(unsigned* rowMaxBits, int* counts){
    int i = blockIdx.x * blockDim.x + threadIdx.x;
    if (i < MQ){ rowMaxBits[i] = 0u; counts[i] = 0; }
}

// fp32 -> bf16 conversion into FRAGMENT-TILED layout.
// Tile = 128 rows x 64 k = 1024 chunks of 16B (8 bf16, consecutive k).
// chunk(r,k) = (((r>>4)*2 + (k>>5))*4 + ((k>>3)&3))*16 + (r&15)
__launch_bounds__(256)
__global__ void convert_tile_kernel(const float* __restrict__ Aq,
                                    const float* __restrict__ Bt,
                                    ushort* __restrict__ Abf,
                                    ushort* __restrict__ Bbf){
    const int bid = blockIdx.x;            // (8 + 1563) * 12 tiles
    const int rt  = bid / KT;
    const int kt  = bid - rt * KT;
    const int tid = threadIdx.x;

    const float* src; ushort* dst; int rowBase, nRows;
    if (rt < 8){
        src = Aq; dst = Abf + (size_t)bid * 8192;
        rowBase = rt * 128; nRows = MQ;
    } else {
        src = Bt; dst = Bbf + (size_t)((rt - 8) * KT + kt) * 8192;
        rowBase = (rt - 8) * 128; nRows = NTRAIN;
    }

    __shared__ ushort tile[8192];   // 16 KB

    #pragma unroll
    for (int i = 0; i < 8; ++i){
        int idx = i * 256 + tid;           // float4 unit, 0..2047
        int r   = idx >> 4;                // 0..127
        int c4  = idx & 15;                // float4 col
        int grow = rowBase + r;
        float4 v = make_float4(0.f, 0.f, 0.f, 0.f);
        if (grow < nRows)
            v = *reinterpret_cast<const float4*>(src + (size_t)grow * KDIM + kt * 64 + c4 * 4);
        ushort4 h; h.x = cvt_bf16(v.x); h.y = cvt_bf16(v.y);
        h.z = cvt_bf16(v.z); h.w = cvt_bf16(v.w);
        int k = c4 * 4;
        int chunk = (((r >> 4) * 2 + (k >> 5)) * 4 + ((k >> 3) & 3)) * 16 + (r & 15);
        *reinterpret_cast<ushort4*>(&tile[chunk * 8 + (k & 7)]) = h;
    }
    __syncthreads();
    #pragma unroll
    for (int i = 0; i < 4; ++i){
        int c = i * 256 + tid;             // chunk id
        *reinterpret_cast<s16x8*>(dst + (size_t)c * 8) =
            *reinterpret_cast<const s16x8*>(&tile[c * 8]);
    }
}

// stage one 128x64 A-tile + B-tile (16KB each) -> 8 gload_lds per thread.
__device__ __forceinline__ void stage_tiles(const ushort* At, const ushort* Bt2,
                                            ushort* As, ushort* Bs, int tid){
    #pragma unroll
    for (int i = 0; i < 4; ++i){
        int c = i * 256 + tid;
        gload_lds16(At + (size_t)c * 8, As + (size_t)c * 8);
    }
    #pragma unroll
    for (int i = 0; i < 4; ++i){
        int c = i * 256 + tid;
        gload_lds16(Bt2 + (size_t)c * 8, Bs + (size_t)c * 8);
    }
}

// 128x128 tile, BK=64 GEMM, DEPTH-3 prefetch pipeline with counted vmcnt:
// 4 LDS buffers; per iter: wait oldest tile (vmcnt(16)) -> barrier ->
// issue stage(kt+3) -> ds_read+MFMA on tile kt. Loads never drained to 0
// in the main loop; ~3 iterations of latency cover per stage.
__launch_bounds__(256)
__global__ void gemm_fast_kernel(const ushort* __restrict__ Abf,
                                 const ushort* __restrict__ Bbf,
                                 unsigned* __restrict__ rowMaxBits,
                                 int* __restrict__ counts,
                                 int* __restrict__ cands){
    const int g   = blockIdx.x;
    const int xcd = g & 7;
    const int l   = g >> 3;
    const int nt  = xcd * 196 + (l >> 3);
    if (nt >= NTILES) return;
    const int m0 = (l & 7) * 128;
    const int n0 = nt * 128;
    const int tid  = threadIdx.x;
    const int lane = tid & 63;
    const int wave = tid >> 6;
    const int wm = (wave >> 1) * 64;
    const int wn = (wave & 1) * 64;
    const int fr = lane & 15;
    const int fg = lane >> 4;
    const int rgA = (wm >> 4);
    const int rgB = (wn >> 4);

    __shared__ union {
        ushort stg[4][16384];     // 4 buffers x (A 16KB | B 16KB) = 128 KB
        float  Csh[64][129];      // 33 KB epilogue staging
    } sm;

    const ushort* Atile = Abf + (size_t)(m0 >> 7) * KT * 8192;
    const ushort* Btile = Bbf + (size_t)nt * KT * 8192;

    f32x4 acc[4][4];
    #pragma unroll
    for (int i = 0; i < 4; ++i)
        #pragma unroll
        for (int j = 0; j < 4; ++j)
            acc[i][j] = (f32x4){0.f, 0.f, 0.f, 0.f};

    auto compute = [&](int kt){
        const ushort* As = &sm.stg[kt & 3][0];
        const ushort* Bs = &sm.stg[kt & 3][8192];
        #pragma unroll
        for (int kk = 0; kk < 2; ++kk){
            s16x8 af[4], bfv[4];
            #pragma unroll
            for (int i = 0; i < 4; ++i){
                int ca = (((rgA + i) * 2 + kk) * 4 + fg) * 16 + fr;
                int cb = (((rgB + i) * 2 + kk) * 4 + fg) * 16 + fr;
                af[i]  = *reinterpret_cast<const s16x8*>(&As[ca * 8]);
                bfv[i] = *reinterpret_cast<const s16x8*>(&Bs[cb * 8]);
            }
            #pragma unroll
            for (int i = 0; i < 4; ++i)
                #pragma unroll
                for (int j = 0; j < 4; ++j)
                    acc[i][j] = __builtin_amdgcn_mfma_f32_16x16x32_bf16(af[i], bfv[j], acc[i][j], 0, 0, 0);
        }
    };

    // prologue: stage tiles 0,1,2 (24 outstanding loads per thread)
    stage_tiles(Atile,                    Btile,                    &sm.stg[0][0], &sm.stg[0][8192], tid);
    stage_tiles(Atile + (size_t)1 * 8192, Btile + (size_t)1 * 8192, &sm.stg[1][0], &sm.stg[1][8192], tid);
    stage_tiles(Atile + (size_t)2 * 8192, Btile + (size_t)2 * 8192, &sm.stg[2][0], &sm.stg[2][8192], tid);

    // main loop: kt = 0..8 stage kt+3 each iter.
    // vmcnt(16): oldest 8 loads (tile kt) retired; 2 newer stages in flight.
    #pragma unroll
    for (int kt = 0; kt < 9; ++kt){
        VMWAIT(16);
        RBARRIER();
        stage_tiles(Atile + (size_t)(kt + 3) * 8192,
                    Btile + (size_t)(kt + 3) * 8192,
                    &sm.stg[(kt + 3) & 3][0], &sm.stg[(kt + 3) & 3][8192], tid);
        compute(kt);
    }
    // peeled tail: no more stages; decreasing wait counts.
    VMWAIT(16); RBARRIER(); compute(9);
    VMWAIT(8);  RBARRIER(); compute(10);
    VMWAIT(0);  RBARRIER(); compute(11);

    // epilogue: two 64-row half-tiles through LDS; 4 threads per row.
    for (int half = 0; half < 2; ++half){
        __syncthreads();
        if ((wave >> 1) == half){
            #pragma unroll
            for (int i = 0; i < 4; ++i)
                #pragma unroll
                for (int j = 0; j < 4; ++j)
                    #pragma unroll
                    for (int q = 0; q < 4; ++q){
                        int rr = i * 16 + (lane >> 4) * 4 + q;
                        int cc = wn + j * 16 + (lane & 15);
                        sm.Csh[rr][cc] = acc[i][j][q];
                    }
        }
        __syncthreads();
        {
            int r = tid >> 2;          // 0..63
            int q = tid & 3;           // 32-col quarter
            int grow = m0 + half * 64 + r;
            float mx = -1e30f;
            #pragma unroll 8
            for (int c = q * 32; c < q * 32 + 32; ++c)
                mx = fmaxf(mx, sm.Csh[r][c]);
            mx = fmaxf(mx, __shfl_xor(mx, 1));
            mx = fmaxf(mx, __shfl_xor(mx, 2));
            float thr = 0.f;
            if (q == 0){
                unsigned old = atomicMax(&rowMaxBits[grow], encf(mx));
                thr = fmaxf(mx, decf(old)) - DELTA;
            }
            thr = __shfl(thr, lane & 60);
            for (int c = q * 32; c < q * 32 + 32; ++c){
                int gcol = n0 + c;
                if (gcol < NTRAIN && sm.Csh[r][c] >= thr){
                    int slot = atomicAdd(&counts[grow], 1);
                    if (slot < CAP) cands[(size_t)grow * CAP + slot] = gcol;
                }
            }
        }
    }
}

// ---- fallback GEMM (round-0 path, used only if ws too small) ----
__launch_bounds__(256)
__global__ void gemm_collect_kernel(const float* __restrict__ Aq,
                                    const float* __restrict__ Bt,
                                    unsigned* __restrict__ rowMaxBits,
                                    int* __restrict__ counts,
                                    int* __restrict__ cands){
    const int m0 = blockIdx.x * 128;
    const int n0 = blockIdx.y * 128;
    const int tid  = threadIdx.x;
    const int lane = tid & 63;
    const int wave = tid >> 6;
    const int wm = (wave >> 1) * 64;
    const int wn = (wave & 1) * 64;

    __shared__ union {
        struct { ushort As[128][32]; ushort Bs[128][32]; } s;
        float Csh[64][129];
    } sm;

    f32x4 acc[4][4];
    #pragma unroll
    for (int i = 0; i < 4; ++i)
        #pragma unroll
        for (int j = 0; j < 4; ++j)
            acc[i][j] = (f32x4){0.f, 0.f, 0.f, 0.f};

    const int fr = lane & 15;
    const int fg = lane >> 4;

    for (int kt = 0; kt < KDIM / 32; ++kt){
        const int k0 = kt * 32;
        __syncthreads();
        #pragma unroll
        for (int i = 0; i < 4; ++i){
            int f  = tid + i * 256;
            int r  = f >> 3;
            int kc = (f & 7) * 4;
            float4 av = *reinterpret_cast<const float4*>(Aq + (size_t)(m0 + r) * KDIM + k0 + kc);
            ushort4 ah; ah.x = cvt_bf16(av.x); ah.y = cvt_bf16(av.y);
            ah.z = cvt_bf16(av.z); ah.w = cvt_bf16(av.w);
            *reinterpret_cast<ushort4*>(&sm.s.As[r][kc]) = ah;
            int nr = n0 + r;
            float4 bv = make_float4(0.f, 0.f, 0.f, 0.f);
            if (nr < NTRAIN)
                bv = *reinterpret_cast<const float4*>(Bt + (size_t)nr * KDIM + k0 + kc);
            ushort4 bh; bh.x = cvt_bf16(bv.x); bh.y = cvt_bf16(bv.y);
            bh.z = cvt_bf16(bv.z); bh.w = cvt_bf16(bv.w);
            *reinterpret_cast<ushort4*>(&sm.s.Bs[r][kc]) = bh;
        }
        __syncthreads();
        s16x8 af[4], bfv[4];
        #pragma unroll
        for (int i = 0; i < 4; ++i){
            af[i]  = *reinterpret_cast<const s16x8*>(&sm.s.As[wm + i * 16 + fr][fg * 8]);
            bfv[i] = *reinterpret_cast<const s16x8*>(&sm.s.Bs[wn + i * 16 + fr][fg * 8]);
        }
        #pragma unroll
        for (int i = 0; i < 4; ++i)
            #pragma unroll
            for (int j = 0; j < 4; ++j)
                acc[i][j] = __builtin_amdgcn_mfma_f32_16x16x32_bf16(af[i], bfv[j], acc[i][j], 0, 0, 0);
    }

    for (int half = 0; half < 2; ++half){
        __syncthreads();
        if ((wave >> 1) == half){
            #pragma unroll
            for (int i = 0; i < 4; ++i)
                #pragma unroll
                for (int j = 0; j < 4; ++j)
                    #pragma unroll
                    for (int q = 0; q < 4; ++q){
                        int rr = i * 16 + (lane >> 4) * 4 + q;
                        int cc = wn + j * 16 + (lane & 15);
                        sm.Csh[rr][cc] = acc[i][j][q];
                    }
        }
        __syncthreads();
        if (tid < 64){
            int grow = m0 + half * 64 + tid;
            float mx = -1e30f;
            #pragma unroll 4
            for (int c = 0; c < 128; ++c) mx = fmaxf(mx, sm.Csh[tid][c]);
            unsigned old = atomicMax(&rowMaxBits[grow], encf(mx));
            float gmax = fmaxf(mx, decf(old));
            float thr = gmax - DELTA;
            for (int c = 0; c < 128; ++c){
                int gcol = n0 + c;
                if (gcol < NTRAIN && sm.Csh[tid][c] >= thr){
                    int slot = atomicAdd(&counts[grow], 1);
                    if (slot < CAP) cands[(size_t)grow * CAP + slot] = gcol;
                }
            }
        }
    }
}

// one block per query row: exact fp32 rescore, top-KSEL, softmax, output.
__launch_bounds__(256)
__global__ void rescore_output_kernel(const float* __restrict__ Aq,
                                      const float* __restrict__ Bt,
                                      const int* __restrict__ labels,
                                      const int* __restrict__ counts,
                                      const int* __restrict__ cands,
                                      float* __restrict__ out){
    const int row  = blockIdx.x;
    const int tid  = threadIdx.x;
    const int lane = tid & 63;
    const int wave = tid >> 6;

    __shared__ float q[KDIM];
    __shared__ float sv[CAP];
    __shared__ float rv[256];
    __shared__ int   ri[256];
    __shared__ float topS[KSEL];
    __shared__ int   topI[KSEL];
    __shared__ float cls[3][NCLS];

    for (int k = tid; k < KDIM; k += 256) q[k] = Aq[(size_t)row * KDIM + k];
    int m = counts[row]; if (m > CAP) m = CAP;
    __syncthreads();

    for (int c = wave; c < m; c += 4){
        int idx = cands[(size_t)row * CAP + c];
        const float* b = Bt + (size_t)idx * KDIM;
        float s = 0.f;
        #pragma unroll
        for (int u = 0; u < 12; ++u){
            int k = lane * 12 + u;
            s += q[k] * b[k];
        }
        #pragma unroll
        for (int off = 32; off; off >>= 1) s += __shfl_down(s, off);
        if (lane == 0) sv[c] = s;
    }
    __syncthreads();

    int msel = m < KSEL ? m : KSEL;
    for (int j = 0; j < msel; ++j){
        float bs = -1e30f; int bi = 0x7FFFFFFF;
        for (int c = tid; c < m; c += 256){
            float v = sv[c];
            if (v > bs){ bs = v; bi = c; }
        }
        rv[tid] = bs; ri[tid] = bi;
        __syncthreads();
        for (int st = 128; st; st >>= 1){
            if (tid < st){
                if (rv[tid + st] > rv[tid] ||
                    (rv[tid + st] == rv[tid] && ri[tid + st] < ri[tid])){
                    rv[tid] = rv[tid + st]; ri[tid] = ri[tid + st];
                }
            }
            __syncthreads();
        }
        if (tid == 0){
            topS[j] = rv[0];
            topI[j] = cands[(size_t)row * CAP + ri[0]];
            sv[ri[0]] = -1e30f;
        }
        __syncthreads();
    }

    for (int i = tid; i < 3 * NCLS; i += 256) (&cls[0][0])[i] = 0.f;
    __syncthreads();

    if (tid == 0){
        float s0 = topS[0];
        float e[KSEL];
        float Z = 0.f;
        for (int j = 0; j < msel; ++j){ e[j] = __expf((topS[j] - s0) * TINV); Z += e[j]; }
        float inv = 1.f / Z;
        for (int j = 0; j < msel; ++j){
            int lb = labels[topI[j]];
            float w = e[j] * inv;
            if (j < 10) cls[0][lb] += w;
            if (j < 50) cls[1][lb] += w;
            cls[2][lb] += w;
        }
    }
    __syncthreads();

    for (int c = tid; c < NCLS; c += 256){
        out[(size_t)row * NCLS + c]                         = cls[0][c];
        out[(size_t)MQ * NCLS + (size_t)row * NCLS + c]     = cls[1][c];
        out[(size_t)2 * MQ * NCLS + (size_t)row * NCLS + c] = cls[2][c];
    }
}

extern "C" void kernel_launch(void* const* d_in, const int* in_sizes, int n_in,
                              void* d_out, int out_size, void* d_ws, size_t ws_size,
                              hipStream_t stream){
    const float* Aq     = (const float*)d_in[0];
    const float* Bt     = (const float*)d_in[1];
    const int*   labels = (const int*)d_in[2];
    float* out = (float*)d_out;

    char* ws = (char*)d_ws;
    unsigned* rowMaxBits = (unsigned*)ws;                         // MQ u32
    int*      counts     = (int*)(ws + (size_t)MQ * 4);           // MQ i32
    int*      cands      = (int*)(ws + (size_t)MQ * 8);           // MQ*CAP i32
    ushort*   Abf        = (ushort*)(ws + (size_t)MQ * 8 + (size_t)MQ * CAP * 4);
    ushort*   Bbf        = Abf + (size_t)8 * KT * 8192;

    const size_t need = (size_t)MQ * 8 + (size_t)MQ * CAP * 4
                      + ((size_t)8 * KT * 8192 + (size_t)NTILES * KT * 8192) * 2;

    hipLaunchKernelGGL(init_kernel, dim3(4), dim3(256), 0, stream, rowMaxBits, counts);

    if (ws_size >= need){
        hipLaunchKernelGGL(convert_tile_kernel, dim3((8 + NTILES) * KT), dim3(256), 0, stream,
                           Aq, Bt, Abf, Bbf);
        hipLaunchKernelGGL(gemm_fast_kernel, dim3(8 * 196 * 8), dim3(256), 0, stream,
                           Abf, Bbf, rowMaxBits, counts, cands);
    } else {
        hipLaunchKernelGGL(gemm_collect_kernel, dim3(8, (NTRAIN + 127) / 128), dim3(256), 0, stream,
                           Aq, Bt, rowMaxBits, counts, cands);
    }
    hipLaunchKernelGGL(rescore_output_kernel, dim3(MQ), dim3(256), 0, stream,
                       Aq, Bt, labels, counts, cands, out);
}

// Round 6
// 814.376 us; speedup vs baseline: 3.7301x; 1.3440x over previous
//
#include <hip/hip_runtime.h>
#include <hip/hip_bf16.h>
#include <math.h>

#define MQ      1024
#define NTRAIN  200000
#define NT256   782             // N-tiles of 256
#define NPAD    200192          // 782 * 256
#define KDIM    768
#define NKT     24              // K-tiles of 32
#define NCLS    1000
#define CAP     1024
#define DELTA   12.0f
#define KSEL    32
#define TINV    (1.0f/0.07f)

typedef short s16x8 __attribute__((ext_vector_type(8)));
typedef float f32x4 __attribute__((ext_vector_type(4)));

__device__ __forceinline__ unsigned encf(float x){
    unsigned u = __float_as_uint(x);
    return (u & 0x80000000u) ? ~u : (u | 0x80000000u);
}
__device__ __forceinline__ float decf(unsigned e){
    unsigned u = (e & 0x80000000u) ? (e & 0x7FFFFFFFu) : ~e;
    return __uint_as_float(u);
}
__device__ __forceinline__ ushort cvt_bf16(float x){
    unsigned u = __float_as_uint(x);
    u += 0x7FFFu + ((u >> 16) & 1u);   // round-to-nearest-even
    return (ushort)(u >> 16);
}
__device__ __forceinline__ void gload_lds16(const void* g, void* l){
    __builtin_amdgcn_global_load_lds(
        (const __attribute__((address_space(1))) unsigned int*)g,
        (__attribute__((address_space(3))) unsigned int*)l, 16, 0, 0);
}

#define VMWAIT(N) asm volatile("s_waitcnt vmcnt(" #N ")" ::: "memory")
#define RBARRIER() do { asm volatile("" ::: "memory"); \
                        __builtin_amdgcn_s_barrier(); \
                        __builtin_amdgcn_sched_barrier(0); \
                        asm volatile("" ::: "memory"); } while (0)
#define PRIO1() __builtin_amdgcn_s_setprio(1)
#define PRIO0() __builtin_amdgcn_s_setprio(0)

__global__ void init_kernel(unsigned* rowMaxBits, int* counts){
    int i = blockIdx.x * blockDim.x + threadIdx.x;
    if (i < MQ){ rowMaxBits[i] = 0u; counts[i] = 0; }
}

// fp32 -> bf16 into FRAGMENT-TILED layout.
// Panel = 256 rows x 32 k = 1024 chunks of 16B (8 bf16 of consecutive k).
// chunk(r,k) = (r>>4)*64 + (k>>3)*16 + (r&15).  A wave's ds_read of fragment
// rg (16 rows x 32 k) is then 1024 CONTIGUOUS LDS bytes -> zero conflicts,
// and global_load_lds staging is a pure linear copy.
__launch_bounds__(256)
__global__ void convert_tile_kernel(const float* __restrict__ Aq,
                                    const float* __restrict__ Bt,
                                    ushort* __restrict__ Abf,
                                    ushort* __restrict__ Bbf){
    const int bid = blockIdx.x;            // (4 + 782) * 24 panels
    const int rt  = bid / NKT;
    const int kt  = bid - rt * NKT;
    const int tid = threadIdx.x;

    const float* src; ushort* dst; int rowBase, nRows;
    if (rt < 4){
        src = Aq; dst = Abf + (size_t)bid * 8192;
        rowBase = rt * 256; nRows = MQ;
    } else {
        src = Bt; dst = Bbf + (size_t)((rt - 4) * NKT + kt) * 8192;
        rowBase = (rt - 4) * 256; nRows = NTRAIN;
    }

    __shared__ ushort tile[8192];   // 16 KB

    #pragma unroll
    for (int i = 0; i < 8; ++i){
        int idx = i * 256 + tid;           // float4 unit, 0..2047
        int r   = idx >> 3;                // 0..255
        int c4  = idx & 7;                 // float4 col within 32-k
        int grow = rowBase + r;
        float4 v = make_float4(0.f, 0.f, 0.f, 0.f);
        if (grow < nRows)
            v = *reinterpret_cast<const float4*>(src + (size_t)grow * KDIM + kt * 32 + c4 * 4);
        ushort4 h; h.x = cvt_bf16(v.x); h.y = cvt_bf16(v.y);
        h.z = cvt_bf16(v.z); h.w = cvt_bf16(v.w);
        int k = c4 * 4;
        int chunk = (r >> 4) * 64 + (k >> 3) * 16 + (r & 15);
        *reinterpret_cast<ushort4*>(&tile[chunk * 8 + (k & 7)]) = h;
    }
    __syncthreads();
    #pragma unroll
    for (int i = 0; i < 4; ++i){
        int c = i * 256 + tid;             // chunk id 0..1023
        *reinterpret_cast<s16x8*>(dst + (size_t)c * 8) =
            *reinterpret_cast<const s16x8*>(&tile[c * 8]);
    }
}

// 256x256 tile, 8 waves, BK=32, 4-buffer depth-2 counted-vmcnt pipeline.
// Per K-tile: 2 phases {stage half of tile t+2 || 8 ds_read -> barrier ->
// setprio(1) 16 MFMA setprio(0) -> barrier}; VMWAIT(4)+barrier once per
// K-tile (stage t+1 stays in flight). Register-direct epilogue.
__launch_bounds__(512, 2)
__global__ void gemm_fast_kernel(const ushort* __restrict__ Abf,
                                 const ushort* __restrict__ Bbf,
                                 unsigned* __restrict__ rowMaxBits,
                                 int* __restrict__ counts,
                                 int* __restrict__ cands){
    const int g    = blockIdx.x;                 // 3128 = 8 * 391
    const int wgid = (g & 7) * 391 + (g >> 3);   // bijective XCD chunking
    const int mt   = wgid & 3;
    const int nt   = wgid >> 2;
    const int tid  = threadIdx.x;
    const int lane = tid & 63;
    const int wave = tid >> 6;
    const int wr   = wave >> 2;      // 0..1  (A half: rows wr*128)
    const int wc   = wave & 3;       // 0..3  (B cols wc*64)
    const int fr   = lane & 15;
    const int fg   = lane >> 4;

    __shared__ ushort lds[4][2][8192];   // [buf][A|B][panel] = 128 KB

    const ushort* Apan = Abf + (size_t)mt * NKT * 8192;
    const ushort* Bpan = Bbf + (size_t)nt * NKT * 8192;

    f32x4 acc[8][4];
    #pragma unroll
    for (int i = 0; i < 8; ++i)
        #pragma unroll
        for (int j = 0; j < 4; ++j)
            acc[i][j] = (f32x4){0.f, 0.f, 0.f, 0.f};

    s16x8 bfrag[4];
    s16x8 afr[4];

    auto stageA = [&](int t){
        const ushort* s = Apan + (size_t)t * 8192;
        ushort* d = &lds[t & 3][0][0];
        #pragma unroll
        for (int i = 0; i < 2; ++i){
            int c = i * 512 + tid;
            gload_lds16(s + (size_t)c * 8, d + (size_t)c * 8);
        }
    };
    auto stageB = [&](int t){
        const ushort* s = Bpan + (size_t)t * 8192;
        ushort* d = &lds[t & 3][1][0];
        #pragma unroll
        for (int i = 0; i < 2; ++i){
            int c = i * 512 + tid;
            gload_lds16(s + (size_t)c * 8, d + (size_t)c * 8);
        }
    };
    auto loadB = [&](int t){
        const ushort* Bs = &lds[t & 3][1][0];
        #pragma unroll
        for (int j = 0; j < 4; ++j){
            int ch = (wc * 4 + j) * 64 + fg * 16 + fr;
            bfrag[j] = *reinterpret_cast<const s16x8*>(&Bs[ch * 8]);
        }
    };

#define LOADA(T, IB) { \
    const ushort* As_ = &lds[(T) & 3][0][0]; \
    _Pragma("unroll") \
    for (int i = 0; i < 4; ++i){ \
        int ch = (wr * 8 + (IB) + i) * 64 + fg * 16 + fr; \
        afr[i] = *reinterpret_cast<const s16x8*>(&As_[ch * 8]); \
    } }

#define MFMA_HALF(IB) { \
    _Pragma("unroll") \
    for (int i = 0; i < 4; ++i) \
        _Pragma("unroll") \
        for (int j = 0; j < 4; ++j) \
            acc[(IB) + i][j] = __builtin_amdgcn_mfma_f32_16x16x32_bf16( \
                afr[i], bfrag[j], acc[(IB) + i][j], 0, 0, 0); }

#define KTILE(T, WAITCODE) { \
    if ((T) + 2 < NKT) stageA((T) + 2); \
    loadB(T); \
    LOADA(T, 0); \
    RBARRIER(); PRIO1(); MFMA_HALF(0); PRIO0(); RBARRIER(); \
    if ((T) + 2 < NKT) stageB((T) + 2); \
    LOADA(T, 4); \
    RBARRIER(); PRIO1(); MFMA_HALF(4); PRIO0(); \
    WAITCODE; RBARRIER(); }

    // prologue: stage tiles 0 and 1 (8 loads/thread outstanding)
    stageA(0); stageB(0); stageA(1); stageB(1);
    VMWAIT(4);      // tile 0 landed; tile 1 still flying
    RBARRIER();

    #pragma unroll
    for (int t = 0; t < 22; ++t) KTILE(t, VMWAIT(4));
    KTILE(22, VMWAIT(0));
    KTILE(23, (void)0);

    // register-direct epilogue: per-row max via 16-lane shfl reduce,
    // global atomicMax, threshold, sparse candidate collect. No LDS.
    {
        const int rbase = mt * 256 + wr * 128 + fg * 4;
        const int cbase = nt * 256 + wc * 64 + fr;
        #pragma unroll
        for (int i = 0; i < 8; ++i){
            #pragma unroll
            for (int q = 0; q < 4; ++q){
                float mx = fmaxf(fmaxf(acc[i][0][q], acc[i][1][q]),
                                 fmaxf(acc[i][2][q], acc[i][3][q]));
                #pragma unroll
                for (int s = 1; s < 16; s <<= 1)
                    mx = fmaxf(mx, __shfl_xor(mx, s));
                int grow = rbase + i * 16 + q;
                float th = 0.f;
                if (fr == 0){
                    unsigned old = atomicMax(&rowMaxBits[grow], encf(mx));
                    th = fmaxf(mx, decf(old)) - DELTA;
                }
                th = __shfl(th, lane & 48);
                #pragma unroll
                for (int j = 0; j < 4; ++j){
                    if (acc[i][j][q] >= th){
                        int gcol = cbase + j * 16;
                        if (gcol < NTRAIN){
                            int slot = atomicAdd(&counts[grow], 1);
                            if (slot < CAP) cands[(size_t)grow * CAP + slot] = gcol;
                        }
                    }
                }
            }
        }
    }
#undef KTILE
#undef MFMA_HALF
#undef LOADA
}

// ---- fallback GEMM (round-0 path, used only if ws too small) ----
__launch_bounds__(256)
__global__ void gemm_collect_kernel(const float* __restrict__ Aq,
                                    const float* __restrict__ Bt,
                                    unsigned* __restrict__ rowMaxBits,
                                    int* __restrict__ counts,
                                    int* __restrict__ cands){
    const int m0 = blockIdx.x * 128;
    const int n0 = blockIdx.y * 128;
    const int tid  = threadIdx.x;
    const int lane = tid & 63;
    const int wave = tid >> 6;
    const int wm = (wave >> 1) * 64;
    const int wn = (wave & 1) * 64;

    __shared__ union {
        struct { ushort As[128][32]; ushort Bs[128][32]; } s;
        float Csh[64][129];
    } sm;

    f32x4 acc[4][4];
    #pragma unroll
    for (int i = 0; i < 4; ++i)
        #pragma unroll
        for (int j = 0; j < 4; ++j)
            acc[i][j] = (f32x4){0.f, 0.f, 0.f, 0.f};

    const int fr = lane & 15;
    const int fg = lane >> 4;

    for (int kt = 0; kt < KDIM / 32; ++kt){
        const int k0 = kt * 32;
        __syncthreads();
        #pragma unroll
        for (int i = 0; i < 4; ++i){
            int f  = tid + i * 256;
            int r  = f >> 3;
            int kc = (f & 7) * 4;
            float4 av = *reinterpret_cast<const float4*>(Aq + (size_t)(m0 + r) * KDIM + k0 + kc);
            ushort4 ah; ah.x = cvt_bf16(av.x); ah.y = cvt_bf16(av.y);
            ah.z = cvt_bf16(av.z); ah.w = cvt_bf16(av.w);
            *reinterpret_cast<ushort4*>(&sm.s.As[r][kc]) = ah;
            int nr = n0 + r;
            float4 bv = make_float4(0.f, 0.f, 0.f, 0.f);
            if (nr < NTRAIN)
                bv = *reinterpret_cast<const float4*>(Bt + (size_t)nr * KDIM + k0 + kc);
            ushort4 bh; bh.x = cvt_bf16(bv.x); bh.y = cvt_bf16(bv.y);
            bh.z = cvt_bf16(bv.z); bh.w = cvt_bf16(bv.w);
            *reinterpret_cast<ushort4*>(&sm.s.Bs[r][kc]) = bh;
        }
        __syncthreads();
        s16x8 af[4], bfv[4];
        #pragma unroll
        for (int i = 0; i < 4; ++i){
            af[i]  = *reinterpret_cast<const s16x8*>(&sm.s.As[wm + i * 16 + fr][fg * 8]);
            bfv[i] = *reinterpret_cast<const s16x8*>(&sm.s.Bs[wn + i * 16 + fr][fg * 8]);
        }
        #pragma unroll
        for (int i = 0; i < 4; ++i)
            #pragma unroll
            for (int j = 0; j < 4; ++j)
                acc[i][j] = __builtin_amdgcn_mfma_f32_16x16x32_bf16(af[i], bfv[j], acc[i][j], 0, 0, 0);
    }

    for (int half = 0; half < 2; ++half){
        __syncthreads();
        if ((wave >> 1) == half){
            #pragma unroll
            for (int i = 0; i < 4; ++i)
                #pragma unroll
                for (int j = 0; j < 4; ++j)
                    #pragma unroll
                    for (int q = 0; q < 4; ++q){
                        int rr = i * 16 + (lane >> 4) * 4 + q;
                        int cc = wn + j * 16 + (lane & 15);
                        sm.Csh[rr][cc] = acc[i][j][q];
                    }
        }
        __syncthreads();
        if (tid < 64){
            int grow = m0 + half * 64 + tid;
            float mx = -1e30f;
            #pragma unroll 4
            for (int c = 0; c < 128; ++c) mx = fmaxf(mx, sm.Csh[tid][c]);
            unsigned old = atomicMax(&rowMaxBits[grow], encf(mx));
            float gmax = fmaxf(mx, decf(old));
            float thr = gmax - DELTA;
            for (int c = 0; c < 128; ++c){
                int gcol = n0 + c;
                if (gcol < NTRAIN && sm.Csh[tid][c] >= thr){
                    int slot = atomicAdd(&counts[grow], 1);
                    if (slot < CAP) cands[(size_t)grow * CAP + slot] = gcol;
                }
            }
        }
    }
}

// one block per query row: exact fp32 rescore, top-KSEL, softmax, output.
__launch_bounds__(256)
__global__ void rescore_output_kernel(const float* __restrict__ Aq,
                                      const float* __restrict__ Bt,
                                      const int* __restrict__ labels,
                                      const int* __restrict__ counts,
                                      const int* __restrict__ cands,
                                      float* __restrict__ out){
    const int row  = blockIdx.x;
    const int tid  = threadIdx.x;
    const int lane = tid & 63;
    const int wave = tid >> 6;

    __shared__ float q[KDIM];
    __shared__ float sv[CAP];
    __shared__ float rv[256];
    __shared__ int   ri[256];
    __shared__ float topS[KSEL];
    __shared__ int   topI[KSEL];
    __shared__ float cls[3][NCLS];

    for (int k = tid; k < KDIM; k += 256) q[k] = Aq[(size_t)row * KDIM + k];
    int m = counts[row]; if (m > CAP) m = CAP;
    __syncthreads();

    for (int c = wave; c < m; c += 4){
        int idx = cands[(size_t)row * CAP + c];
        const float* b = Bt + (size_t)idx * KDIM;
        float s = 0.f;
        #pragma unroll
        for (int u = 0; u < 12; ++u){
            int k = lane * 12 + u;
            s += q[k] * b[k];
        }
        #pragma unroll
        for (int off = 32; off; off >>= 1) s += __shfl_down(s, off);
        if (lane == 0) sv[c] = s;
    }
    __syncthreads();

    int msel = m < KSEL ? m : KSEL;
    for (int j = 0; j < msel; ++j){
        float bs = -1e30f; int bi = 0x7FFFFFFF;
        for (int c = tid; c < m; c += 256){
            float v = sv[c];
            if (v > bs){ bs = v; bi = c; }
        }
        rv[tid] = bs; ri[tid] = bi;
        __syncthreads();
        for (int st = 128; st; st >>= 1){
            if (tid < st){
                if (rv[tid + st] > rv[tid] ||
                    (rv[tid + st] == rv[tid] && ri[tid + st] < ri[tid])){
                    rv[tid] = rv[tid + st]; ri[tid] = ri[tid + st];
                }
            }
            __syncthreads();
        }
        if (tid == 0){
            topS[j] = rv[0];
            topI[j] = cands[(size_t)row * CAP + ri[0]];
            sv[ri[0]] = -1e30f;
        }
        __syncthreads();
    }

    for (int i = tid; i < 3 * NCLS; i += 256) (&cls[0][0])[i] = 0.f;
    __syncthreads();

    if (tid == 0){
        float s0 = topS[0];
        float e[KSEL];
        float Z = 0.f;
        for (int j = 0; j < msel; ++j){ e[j] = __expf((topS[j] - s0) * TINV); Z += e[j]; }
        float inv = 1.f / Z;
        for (int j = 0; j < msel; ++j){
            int lb = labels[topI[j]];
            float w = e[j] * inv;
            if (j < 10) cls[0][lb] += w;
            if (j < 50) cls[1][lb] += w;
            cls[2][lb] += w;
        }
    }
    __syncthreads();

    for (int c = tid; c < NCLS; c += 256){
        out[(size_t)row * NCLS + c]                         = cls[0][c];
        out[(size_t)MQ * NCLS + (size_t)row * NCLS + c]     = cls[1][c];
        out[(size_t)2 * MQ * NCLS + (size_t)row * NCLS + c] = cls[2][c];
    }
}

extern "C" void kernel_launch(void* const* d_in, const int* in_sizes, int n_in,
                              void* d_out, int out_size, void* d_ws, size_t ws_size,
                              hipStream_t stream){
    const float* Aq     = (const float*)d_in[0];
    const float* Bt     = (const float*)d_in[1];
    const int*   labels = (const int*)d_in[2];
    float* out = (float*)d_out;

    char* ws = (char*)d_ws;
    unsigned* rowMaxBits = (unsigned*)ws;                         // MQ u32
    int*      counts     = (int*)(ws + (size_t)MQ * 4);           // MQ i32
    int*      cands      = (int*)(ws + (size_t)MQ * 8);           // MQ*CAP i32
    ushort*   Abf        = (ushort*)(ws + (size_t)MQ * 8 + (size_t)MQ * CAP * 4);
    ushort*   Bbf        = Abf + (size_t)4 * NKT * 8192;

    const size_t need = (size_t)MQ * 8 + (size_t)MQ * CAP * 4
                      + ((size_t)4 * NKT * 8192 + (size_t)NT256 * NKT * 8192) * 2;

    hipLaunchKernelGGL(init_kernel, dim3(4), dim3(256), 0, stream, rowMaxBits, counts);

    if (ws_size >= need){
        hipLaunchKernelGGL(convert_tile_kernel, dim3((4 + NT256) * NKT), dim3(256), 0, stream,
                           Aq, Bt, Abf, Bbf);
        hipLaunchKernelGGL(gemm_fast_kernel, dim3(8 * 391), dim3(512), 0, stream,
                           Abf, Bbf, rowMaxBits, counts, cands);
    } else {
        hipLaunchKernelGGL(gemm_collect_kernel, dim3(8, (NTRAIN + 127) / 128), dim3(256), 0, stream,
                           Aq, Bt, rowMaxBits, counts, cands);
    }
    hipLaunchKernelGGL(rescore_output_kernel, dim3(MQ), dim3(256), 0, stream,
                       Aq, Bt, labels, counts, cands, out);
}

// Round 7
// 738.707 us; speedup vs baseline: 4.1122x; 1.1024x over previous
//
#include <hip/hip_runtime.h>
#include <hip/hip_bf16.h>
#include <math.h>

#define MQ      1024
#define NTRAIN  200000
#define NT256   782             // N-tiles of 256
#define KDIM    768
#define NKT     24              // K-tiles of 32
#define NCLS    1000
#define CAP     1024
#define DELTA   8.0f
#define KSEL    32
#define TINV    (1.0f/0.07f)

typedef short s16x8  __attribute__((ext_vector_type(8)));
typedef float f32x4  __attribute__((ext_vector_type(4)));
typedef float f32x16 __attribute__((ext_vector_type(16)));

__device__ __forceinline__ unsigned encf(float x){
    unsigned u = __float_as_uint(x);
    return (u & 0x80000000u) ? ~u : (u | 0x80000000u);
}
__device__ __forceinline__ float decf(unsigned e){
    unsigned u = (e & 0x80000000u) ? (e & 0x7FFFFFFFu) : ~e;
    return __uint_as_float(u);
}
__device__ __forceinline__ ushort cvt_bf16(float x){
    unsigned u = __float_as_uint(x);
    u += 0x7FFFu + ((u >> 16) & 1u);   // round-to-nearest-even
    return (ushort)(u >> 16);
}
__device__ __forceinline__ void gload_lds16(const void* g, void* l){
    __builtin_amdgcn_global_load_lds(
        (const __attribute__((address_space(1))) unsigned int*)g,
        (__attribute__((address_space(3))) unsigned int*)l, 16, 0, 0);
}

#define VMWAIT(N) asm volatile("s_waitcnt vmcnt(" #N ")" ::: "memory")
#define RBAR()    asm volatile("s_barrier" ::: "memory")
#define PRIO1()   __builtin_amdgcn_s_setprio(1)
#define PRIO0()   __builtin_amdgcn_s_setprio(0)

__global__ void init_kernel(unsigned* rowMaxBits, int* counts){
    int i = blockIdx.x * blockDim.x + threadIdx.x;
    if (i < MQ){ rowMaxBits[i] = 0u; counts[i] = 0; }
}

// fp32 -> bf16 into 32x32x16-FRAGMENT-TILED layout.
// Panel = 256 rows x 32 k = 16 frags (8 rowblk x 2 kslot) of 64 chunks.
// Element (r,k): frag = (r>>5)*2 + (k>>4); lane-chunk = (r&31) + 32*((k>>3)&1);
// byte j = k&7.  A wave's ds_read of one frag = 64 consecutive chunks (1 KB)
// -> zero bank conflicts; global_load_lds staging is a pure linear copy.
__launch_bounds__(256)
__global__ void convert_tile_kernel(const float* __restrict__ Aq,
                                    const float* __restrict__ Bt,
                                    ushort* __restrict__ Abf,
                                    ushort* __restrict__ Bbf){
    const int bid = blockIdx.x;            // (4 + 782) * 24 panels
    const int rt  = bid / NKT;
    const int kt  = bid - rt * NKT;
    const int tid = threadIdx.x;

    const float* src; ushort* dst; int rowBase, nRows;
    if (rt < 4){
        src = Aq; dst = Abf + (size_t)bid * 8192;
        rowBase = rt * 256; nRows = MQ;
    } else {
        src = Bt; dst = Bbf + (size_t)((rt - 4) * NKT + kt) * 8192;
        rowBase = (rt - 4) * 256; nRows = NTRAIN;
    }

    __shared__ ushort tile[8192];   // 16 KB

    #pragma unroll
    for (int i = 0; i < 8; ++i){
        int idx = i * 256 + tid;           // float4 unit, 0..2047
        int r   = idx >> 3;                // 0..255
        int c4  = idx & 7;                 // float4 col within 32-k
        int grow = rowBase + r;
        float4 v = make_float4(0.f, 0.f, 0.f, 0.f);
        if (grow < nRows)
            v = *reinterpret_cast<const float4*>(src + (size_t)grow * KDIM + kt * 32 + c4 * 4);
        ushort4 h; h.x = cvt_bf16(v.x); h.y = cvt_bf16(v.y);
        h.z = cvt_bf16(v.z); h.w = cvt_bf16(v.w);
        int k = c4 * 4;
        int chunk = ((r >> 5) * 2 + (k >> 4)) * 64 + (r & 31) + 32 * ((k >> 3) & 1);
        *reinterpret_cast<ushort4*>(&tile[chunk * 8 + (k & 7)]) = h;
    }
    __syncthreads();
    #pragma unroll
    for (int i = 0; i < 4; ++i){
        int c = i * 256 + tid;             // chunk id 0..1023
        *reinterpret_cast<s16x8*>(dst + (size_t)c * 8) =
            *reinterpret_cast<const s16x8*>(&tile[c * 8]);
    }
}

// 256x256 tile, 8 waves, BK=32, 32x32x16 MFMA, 4-buffer depth-2 pipeline,
// ONE barrier per K-tile: stage(t+2) + 12 ds_read + 16 MFMA, then
// VMWAIT(4)+s_barrier. Waves skew freely inside the tile (MFMA of one wave
// overlaps ds_reads of another); counted vmcnt keeps 2 stages in flight.
__launch_bounds__(512, 2)
__global__ void gemm_fast_kernel(const ushort* __restrict__ Abf,
                                 const ushort* __restrict__ Bbf,
                                 unsigned* __restrict__ rowMaxBits,
                                 int* __restrict__ counts,
                                 int* __restrict__ cands){
    const int g    = blockIdx.x;                 // 3128 = 8 * 391
    const int wgid = (g & 7) * 391 + (g >> 3);   // bijective XCD chunking
    const int mt   = wgid & 3;
    const int nt   = wgid >> 2;
    const int tid  = threadIdx.x;
    const int lane = tid & 63;
    const int wave = tid >> 6;
    const int wr   = wave >> 2;      // 0..1  rows wr*128
    const int wc   = wave & 3;       // 0..3  cols wc*64
    const int lh   = lane >> 5;
    const int lm   = lane & 31;

    __shared__ union {
        ushort stg[4][2][8192];                       // 128 KB staging
        struct { float redmax[256][4]; float ths[256]; } ep;
    } sm;

    const ushort* Apan = Abf + (size_t)mt * NKT * 8192;
    const ushort* Bpan = Bbf + (size_t)nt * NKT * 8192;

    f32x16 acc[4][2];
    #pragma unroll
    for (int i = 0; i < 4; ++i)
        #pragma unroll
        for (int j = 0; j < 2; ++j)
            #pragma unroll
            for (int q = 0; q < 16; ++q)
                acc[i][j][q] = 0.f;

    auto stageAB = [&](int t){
        const ushort* sa = Apan + (size_t)t * 8192;
        const ushort* sb = Bpan + (size_t)t * 8192;
        ushort* da = &sm.stg[t & 3][0][0];
        ushort* db = &sm.stg[t & 3][1][0];
        #pragma unroll
        for (int i = 0; i < 2; ++i){
            int c = i * 512 + tid;
            gload_lds16(sa + (size_t)c * 8, da + (size_t)c * 8);
        }
        #pragma unroll
        for (int i = 0; i < 2; ++i){
            int c = i * 512 + tid;
            gload_lds16(sb + (size_t)c * 8, db + (size_t)c * 8);
        }
    };

    auto ktile = [&](int t){
        const ushort* As = &sm.stg[t & 3][0][0];
        const ushort* Bs = &sm.stg[t & 3][1][0];
        s16x8 aq[4][2], bq[2][2];
        #pragma unroll
        for (int cf = 0; cf < 2; ++cf)
            #pragma unroll
            for (int ks = 0; ks < 2; ++ks)
                bq[cf][ks] = *reinterpret_cast<const s16x8*>(
                    &Bs[(((wc * 2 + cf) * 2 + ks) * 64 + lane) * 8]);
        #pragma unroll
        for (int rf = 0; rf < 4; ++rf)
            #pragma unroll
            for (int ks = 0; ks < 2; ++ks)
                aq[rf][ks] = *reinterpret_cast<const s16x8*>(
                    &As[(((wr * 4 + rf) * 2 + ks) * 64 + lane) * 8]);
        PRIO1();
        #pragma unroll
        for (int ks = 0; ks < 2; ++ks)
            #pragma unroll
            for (int rf = 0; rf < 4; ++rf)
                #pragma unroll
                for (int cf = 0; cf < 2; ++cf)
                    acc[rf][cf] = __builtin_amdgcn_mfma_f32_32x32x16_bf16(
                        aq[rf][ks], bq[cf][ks], acc[rf][cf], 0, 0, 0);
        PRIO0();
    };

    // prologue: stage tiles 0 and 1 (8 loads/thread)
    stageAB(0); stageAB(1);
    VMWAIT(4);      // tile 0 landed; tile 1 flying
    RBAR();

    #pragma unroll 2
    for (int t = 0; t < NKT - 2; ++t){
        stageAB(t + 2);       // 4 loads, lands ~2 K-tiles later
        ktile(t);
        VMWAIT(4);            // tile t+1 landed; t+2 flying
        RBAR();
    }
    ktile(NKT - 2);
    VMWAIT(0);
    RBAR();
    ktile(NKT - 1);

    // ---- epilogue: cross-wc row-max reduce, 1 atomicMax/row, collect ----
    __syncthreads();
    #pragma unroll
    for (int rf = 0; rf < 4; ++rf)
        #pragma unroll
        for (int q = 0; q < 16; ++q){
            float v = fmaxf(acc[rf][0][q], acc[rf][1][q]);
            v = fmaxf(v, __shfl_xor(v, 1));
            v = fmaxf(v, __shfl_xor(v, 2));
            v = fmaxf(v, __shfl_xor(v, 4));
            v = fmaxf(v, __shfl_xor(v, 8));
            v = fmaxf(v, __shfl_xor(v, 16));
            if (lm == 0){
                int row = wr * 128 + rf * 32 + (q & 3) + 8 * (q >> 2) + 4 * lh;
                sm.ep.redmax[row][wc] = v;
            }
        }
    __syncthreads();
    if (tid < 256){
        float m = fmaxf(fmaxf(sm.ep.redmax[tid][0], sm.ep.redmax[tid][1]),
                        fmaxf(sm.ep.redmax[tid][2], sm.ep.redmax[tid][3]));
        unsigned old = atomicMax(&rowMaxBits[mt * 256 + tid], encf(m));
        sm.ep.ths[tid] = fmaxf(m, decf(old)) - DELTA;
    }
    __syncthreads();
    #pragma unroll
    for (int rf = 0; rf < 4; ++rf)
        #pragma unroll
        for (int q = 0; q < 16; ++q){
            int row = wr * 128 + rf * 32 + (q & 3) + 8 * (q >> 2) + 4 * lh;
            float thr = sm.ep.ths[row];
            #pragma unroll
            for (int cf = 0; cf < 2; ++cf){
                if (acc[rf][cf][q] >= thr){
                    int gcol = nt * 256 + wc * 64 + cf * 32 + lm;
                    if (gcol < NTRAIN){
                        int grow = mt * 256 + row;
                        int slot = atomicAdd(&counts[grow], 1);
                        if (slot < CAP) cands[(size_t)grow * CAP + slot] = gcol;
                    }
                }
            }
        }
}

// ---- fallback GEMM (round-0 path, used only if ws too small) ----
__launch_bounds__(256)
__global__ void gemm_collect_kernel(const float* __restrict__ Aq,
                                    const float* __restrict__ Bt,
                                    unsigned* __restrict__ rowMaxBits,
                                    int* __restrict__ counts,
                                    int* __restrict__ cands){
    const int m0 = blockIdx.x * 128;
    const int n0 = blockIdx.y * 128;
    const int tid  = threadIdx.x;
    const int lane = tid & 63;
    const int wave = tid >> 6;
    const int wm = (wave >> 1) * 64;
    const int wn = (wave & 1) * 64;

    __shared__ union {
        struct { ushort As[128][32]; ushort Bs[128][32]; } s;
        float Csh[64][129];
    } sm;

    f32x4 acc[4][4];
    #pragma unroll
    for (int i = 0; i < 4; ++i)
        #pragma unroll
        for (int j = 0; j < 4; ++j)
            acc[i][j] = (f32x4){0.f, 0.f, 0.f, 0.f};

    const int fr = lane & 15;
    const int fg = lane >> 4;

    for (int kt = 0; kt < KDIM / 32; ++kt){
        const int k0 = kt * 32;
        __syncthreads();
        #pragma unroll
        for (int i = 0; i < 4; ++i){
            int f  = tid + i * 256;
            int r  = f >> 3;
            int kc = (f & 7) * 4;
            float4 av = *reinterpret_cast<const float4*>(Aq + (size_t)(m0 + r) * KDIM + k0 + kc);
            ushort4 ah; ah.x = cvt_bf16(av.x); ah.y = cvt_bf16(av.y);
            ah.z = cvt_bf16(av.z); ah.w = cvt_bf16(av.w);
            *reinterpret_cast<ushort4*>(&sm.s.As[r][kc]) = ah;
            int nr = n0 + r;
            float4 bv = make_float4(0.f, 0.f, 0.f, 0.f);
            if (nr < NTRAIN)
                bv = *reinterpret_cast<const float4*>(Bt + (size_t)nr * KDIM + k0 + kc);
            ushort4 bh; bh.x = cvt_bf16(bv.x); bh.y = cvt_bf16(bv.y);
            bh.z = cvt_bf16(bv.z); bh.w = cvt_bf16(bv.w);
            *reinterpret_cast<ushort4*>(&sm.s.Bs[r][kc]) = bh;
        }
        __syncthreads();
        s16x8 af[4], bfv[4];
        #pragma unroll
        for (int i = 0; i < 4; ++i){
            af[i]  = *reinterpret_cast<const s16x8*>(&sm.s.As[wm + i * 16 + fr][fg * 8]);
            bfv[i] = *reinterpret_cast<const s16x8*>(&sm.s.Bs[wn + i * 16 + fr][fg * 8]);
        }
        #pragma unroll
        for (int i = 0; i < 4; ++i)
            #pragma unroll
            for (int j = 0; j < 4; ++j)
                acc[i][j] = __builtin_amdgcn_mfma_f32_16x16x32_bf16(af[i], bfv[j], acc[i][j], 0, 0, 0);
    }

    for (int half = 0; half < 2; ++half){
        __syncthreads();
        if ((wave >> 1) == half){
            #pragma unroll
            for (int i = 0; i < 4; ++i)
                #pragma unroll
                for (int j = 0; j < 4; ++j)
                    #pragma unroll
                    for (int q = 0; q < 4; ++q){
                        int rr = i * 16 + (lane >> 4) * 4 + q;
                        int cc = wn + j * 16 + (lane & 15);
                        sm.Csh[rr][cc] = acc[i][j][q];
                    }
        }
        __syncthreads();
        if (tid < 64){
            int grow = m0 + half * 64 + tid;
            float mx = -1e30f;
            #pragma unroll 4
            for (int c = 0; c < 128; ++c) mx = fmaxf(mx, sm.Csh[tid][c]);
            unsigned old = atomicMax(&rowMaxBits[grow], encf(mx));
            float gmax = fmaxf(mx, decf(old));
            float thr = gmax - DELTA;
            for (int c = 0; c < 128; ++c){
                int gcol = n0 + c;
                if (gcol < NTRAIN && sm.Csh[tid][c] >= thr){
                    int slot = atomicAdd(&counts[grow], 1);
                    if (slot < CAP) cands[(size_t)grow * CAP + slot] = gcol;
                }
            }
        }
    }
}

// one block per query row: exact fp32 rescore, top-KSEL, softmax, output.
__launch_bounds__(256)
__global__ void rescore_output_kernel(const float* __restrict__ Aq,
                                      const float* __restrict__ Bt,
                                      const int* __restrict__ labels,
                                      const int* __restrict__ counts,
                                      const int* __restrict__ cands,
                                      float* __restrict__ out){
    const int row  = blockIdx.x;
    const int tid  = threadIdx.x;
    const int lane = tid & 63;
    const int wave = tid >> 6;

    __shared__ float q[KDIM];
    __shared__ float sv[CAP];
    __shared__ float rv[256];
    __shared__ int   ri[256];
    __shared__ float topS[KSEL];
    __shared__ int   topI[KSEL];
    __shared__ float cls[3][NCLS];

    for (int k = tid; k < KDIM; k += 256) q[k] = Aq[(size_t)row * KDIM + k];
    int m = counts[row]; if (m > CAP) m = CAP;
    __syncthreads();

    for (int c = wave; c < m; c += 4){
        int idx = cands[(size_t)row * CAP + c];
        const float* b = Bt + (size_t)idx * KDIM;
        float s = 0.f;
        #pragma unroll
        for (int u = 0; u < 12; ++u){
            int k = lane * 12 + u;
            s += q[k] * b[k];
        }
        #pragma unroll
        for (int off = 32; off; off >>= 1) s += __shfl_down(s, off);
        if (lane == 0) sv[c] = s;
    }
    __syncthreads();

    int msel = m < KSEL ? m : KSEL;
    for (int j = 0; j < msel; ++j){
        float bs = -1e30f; int bi = 0x7FFFFFFF;
        for (int c = tid; c < m; c += 256){
            float v = sv[c];
            if (v > bs){ bs = v; bi = c; }
        }
        rv[tid] = bs; ri[tid] = bi;
        __syncthreads();
        for (int st = 128; st; st >>= 1){
            if (tid < st){
                if (rv[tid + st] > rv[tid] ||
                    (rv[tid + st] == rv[tid] && ri[tid + st] < ri[tid])){
                    rv[tid] = rv[tid + st]; ri[tid] = ri[tid + st];
                }
            }
            __syncthreads();
        }
        if (tid == 0){
            topS[j] = rv[0];
            topI[j] = cands[(size_t)row * CAP + ri[0]];
            sv[ri[0]] = -1e30f;
        }
        __syncthreads();
    }

    for (int i = tid; i < 3 * NCLS; i += 256) (&cls[0][0])[i] = 0.f;
    __syncthreads();

    if (tid == 0){
        float s0 = topS[0];
        float e[KSEL];
        float Z = 0.f;
        for (int j = 0; j < msel; ++j){ e[j] = __expf((topS[j] - s0) * TINV); Z += e[j]; }
        float inv = 1.f / Z;
        for (int j = 0; j < msel; ++j){
            int lb = labels[topI[j]];
            float w = e[j] * inv;
            if (j < 10) cls[0][lb] += w;
            if (j < 50) cls[1][lb] += w;
            cls[2][lb] += w;
        }
    }
    __syncthreads();

    for (int c = tid; c < NCLS; c += 256){
        out[(size_t)row * NCLS + c]                         = cls[0][c];
        out[(size_t)MQ * NCLS + (size_t)row * NCLS + c]     = cls[1][c];
        out[(size_t)2 * MQ * NCLS + (size_t)row * NCLS + c] = cls[2][c];
    }
}

extern "C" void kernel_launch(void* const* d_in, const int* in_sizes, int n_in,
                              void* d_out, int out_size, void* d_ws, size_t ws_size,
                              hipStream_t stream){
    const float* Aq     = (const float*)d_in[0];
    const float* Bt     = (const float*)d_in[1];
    const int*   labels = (const int*)d_in[2];
    float* out = (float*)d_out;

    char* ws = (char*)d_ws;
    unsigned* rowMaxBits = (unsigned*)ws;                         // MQ u32
    int*      counts     = (int*)(ws + (size_t)MQ * 4);           // MQ i32
    int*      cands      = (int*)(ws + (size_t)MQ * 8);           // MQ*CAP i32
    ushort*   Abf        = (ushort*)(ws + (size_t)MQ * 8 + (size_t)MQ * CAP * 4);
    ushort*   Bbf        = Abf + (size_t)4 * NKT * 8192;

    const size_t need = (size_t)MQ * 8 + (size_t)MQ * CAP * 4
                      + ((size_t)4 * NKT * 8192 + (size_t)NT256 * NKT * 8192) * 2;

    hipLaunchKernelGGL(init_kernel, dim3(4), dim3(256), 0, stream, rowMaxBits, counts);

    if (ws_size >= need){
        hipLaunchKernelGGL(convert_tile_kernel, dim3((4 + NT256) * NKT), dim3(256), 0, stream,
                           Aq, Bt, Abf, Bbf);
        hipLaunchKernelGGL(gemm_fast_kernel, dim3(8 * 391), dim3(512), 0, stream,
                           Abf, Bbf, rowMaxBits, counts, cands);
    } else {
        hipLaunchKernelGGL(gemm_collect_kernel, dim3(8, (NTRAIN + 127) / 128), dim3(256), 0, stream,
                           Aq, Bt, rowMaxBits, counts, cands);
    }
    hipLaunchKernelGGL(rescore_output_kernel, dim3(MQ), dim3(256), 0, stream,
                       Aq, Bt, labels, counts, cands, out);
}

// Round 8
// 734.580 us; speedup vs baseline: 4.1353x; 1.0056x over previous
//
#include <hip/hip_runtime.h>
#include <hip/hip_bf16.h>
#include <math.h>

#define MQ      1024
#define NTRAIN  200000
#define NT256   782             // N-tiles of 256
#define KDIM    768
#define NKT     24              // K-tiles of 32
#define NCLS    1000
#define CAP     1024
#define DELTA   8.0f
#define KSEL    32
#define TINV    (1.0f/0.07f)

typedef short s16x8  __attribute__((ext_vector_type(8)));
typedef float f32x4  __attribute__((ext_vector_type(4)));
typedef float f32x16 __attribute__((ext_vector_type(16)));

__device__ __forceinline__ unsigned encf(float x){
    unsigned u = __float_as_uint(x);
    return (u & 0x80000000u) ? ~u : (u | 0x80000000u);
}
__device__ __forceinline__ float decf(unsigned e){
    unsigned u = (e & 0x80000000u) ? (e & 0x7FFFFFFFu) : ~e;
    return __uint_as_float(u);
}
__device__ __forceinline__ ushort cvt_bf16(float x){
    unsigned u = __float_as_uint(x);
    u += 0x7FFFu + ((u >> 16) & 1u);   // round-to-nearest-even
    return (ushort)(u >> 16);
}
__device__ __forceinline__ void gload_lds16(const void* g, void* l){
    __builtin_amdgcn_global_load_lds(
        (const __attribute__((address_space(1))) unsigned int*)g,
        (__attribute__((address_space(3))) unsigned int*)l, 16, 0, 0);
}

#define VMWAIT(N) asm volatile("s_waitcnt vmcnt(" #N ")" ::: "memory")
#define RBAR()    asm volatile("s_barrier" ::: "memory")
#define PRIO1()   __builtin_amdgcn_s_setprio(1)
#define PRIO0()   __builtin_amdgcn_s_setprio(0)

__global__ void init_kernel(unsigned* rowMaxBits, int* counts){
    int i = blockIdx.x * blockDim.x + threadIdx.x;
    if (i < MQ){ rowMaxBits[i] = 0u; counts[i] = 0; }
}

// fp32 -> bf16 into 32x32x16-FRAGMENT-TILED layout.
// Panel = 256 rows x 32 k; chunk(r,k) = ((r>>5)*2 + (k>>4))*64 + (r&31)
// + 32*((k>>3)&1), byte j = k&7.  A wave's fragment ds_read = 64 consecutive
// chunks (1 KB) -> zero conflicts; staging is a pure linear copy.
__launch_bounds__(256)
__global__ void convert_tile_kernel(const float* __restrict__ Aq,
                                    const float* __restrict__ Bt,
                                    ushort* __restrict__ Abf,
                                    ushort* __restrict__ Bbf){
    const int bid = blockIdx.x;            // (4 + 782) * 24 panels
    const int rt  = bid / NKT;
    const int kt  = bid - rt * NKT;
    const int tid = threadIdx.x;

    const float* src; ushort* dst; int rowBase, nRows;
    if (rt < 4){
        src = Aq; dst = Abf + (size_t)bid * 8192;
        rowBase = rt * 256; nRows = MQ;
    } else {
        src = Bt; dst = Bbf + (size_t)((rt - 4) * NKT + kt) * 8192;
        rowBase = (rt - 4) * 256; nRows = NTRAIN;
    }

    __shared__ ushort tile[8192];   // 16 KB

    #pragma unroll
    for (int i = 0; i < 8; ++i){
        int idx = i * 256 + tid;           // float4 unit, 0..2047
        int r   = idx >> 3;                // 0..255
        int c4  = idx & 7;                 // float4 col within 32-k
        int grow = rowBase + r;
        float4 v = make_float4(0.f, 0.f, 0.f, 0.f);
        if (grow < nRows)
            v = *reinterpret_cast<const float4*>(src + (size_t)grow * KDIM + kt * 32 + c4 * 4);
        ushort4 h; h.x = cvt_bf16(v.x); h.y = cvt_bf16(v.y);
        h.z = cvt_bf16(v.z); h.w = cvt_bf16(v.w);
        int k = c4 * 4;
        int chunk = ((r >> 5) * 2 + (k >> 4)) * 64 + (r & 31) + 32 * ((k >> 3) & 1);
        *reinterpret_cast<ushort4*>(&tile[chunk * 8 + (k & 7)]) = h;
    }
    __syncthreads();
    #pragma unroll
    for (int i = 0; i < 4; ++i){
        int c = i * 256 + tid;             // chunk id 0..1023
        *reinterpret_cast<s16x8*>(dst + (size_t)c * 8) =
            *reinterpret_cast<const s16x8*>(&tile[c * 8]);
    }
}

// 256x256 tile, 8 waves, BK=32, 32x32x16 MFMA, 4-buffer depth-2 global
// pipeline PLUS register-level fragment ping-pong: each half-K's 6 ds_reads
// fly under the other half's 8 MFMAs. One barrier + one counted vmcnt per
// K-tile; loads never drained to 0 until the tail.
__launch_bounds__(512, 2)
__global__ void gemm_fast_kernel(const ushort* __restrict__ Abf,
                                 const ushort* __restrict__ Bbf,
                                 unsigned* __restrict__ rowMaxBits,
                                 int* __restrict__ counts,
                                 int* __restrict__ cands){
    const int g    = blockIdx.x;                 // 3128 = 8 * 391
    const int wgid = (g & 7) * 391 + (g >> 3);   // bijective XCD chunking
    const int mt   = wgid & 3;
    const int nt   = wgid >> 2;
    const int tid  = threadIdx.x;
    const int lane = tid & 63;
    const int wave = tid >> 6;
    const int wr   = wave >> 2;      // 0..1  rows wr*128
    const int wc   = wave & 3;       // 0..3  cols wc*64
    const int lh   = lane >> 5;
    const int lm   = lane & 31;

    __shared__ union {
        ushort stg[4][2][8192];                       // 128 KB staging
        struct { float redmax[256][4]; float ths[256]; } ep;
    } sm;

    const ushort* Apan = Abf + (size_t)mt * NKT * 8192;
    const ushort* Bpan = Bbf + (size_t)nt * NKT * 8192;

    f32x16 acc[4][2];
    #pragma unroll
    for (int i = 0; i < 4; ++i)
        #pragma unroll
        for (int j = 0; j < 2; ++j)
            #pragma unroll
            for (int q = 0; q < 16; ++q)
                acc[i][j][q] = 0.f;

    // two named fragment sets: set0 = ks=0 frags, set1 = ks=1 frags
    s16x8 aq0[4], aq1[4], bq0[2], bq1[2];

    auto stageAB = [&](int t){
        const ushort* sa = Apan + (size_t)t * 8192;
        const ushort* sb = Bpan + (size_t)t * 8192;
        ushort* da = &sm.stg[t & 3][0][0];
        ushort* db = &sm.stg[t & 3][1][0];
        #pragma unroll
        for (int i = 0; i < 2; ++i){
            int c = i * 512 + tid;
            gload_lds16(sa + (size_t)c * 8, da + (size_t)c * 8);
        }
        #pragma unroll
        for (int i = 0; i < 2; ++i){
            int c = i * 512 + tid;
            gload_lds16(sb + (size_t)c * 8, db + (size_t)c * 8);
        }
    };
    auto read0 = [&](int t){
        const ushort* As = &sm.stg[t & 3][0][0];
        const ushort* Bs = &sm.stg[t & 3][1][0];
        #pragma unroll
        for (int cf = 0; cf < 2; ++cf)
            bq0[cf] = *reinterpret_cast<const s16x8*>(
                &Bs[(((wc * 2 + cf) * 2 + 0) * 64 + lane) * 8]);
        #pragma unroll
        for (int rf = 0; rf < 4; ++rf)
            aq0[rf] = *reinterpret_cast<const s16x8*>(
                &As[(((wr * 4 + rf) * 2 + 0) * 64 + lane) * 8]);
    };
    auto read1 = [&](int t){
        const ushort* As = &sm.stg[t & 3][0][0];
        const ushort* Bs = &sm.stg[t & 3][1][0];
        #pragma unroll
        for (int cf = 0; cf < 2; ++cf)
            bq1[cf] = *reinterpret_cast<const s16x8*>(
                &Bs[(((wc * 2 + cf) * 2 + 1) * 64 + lane) * 8]);
        #pragma unroll
        for (int rf = 0; rf < 4; ++rf)
            aq1[rf] = *reinterpret_cast<const s16x8*>(
                &As[(((wr * 4 + rf) * 2 + 1) * 64 + lane) * 8]);
    };
    auto mfma0 = [&]{
        PRIO1();
        #pragma unroll
        for (int rf = 0; rf < 4; ++rf)
            #pragma unroll
            for (int cf = 0; cf < 2; ++cf)
                acc[rf][cf] = __builtin_amdgcn_mfma_f32_32x32x16_bf16(
                    aq0[rf], bq0[cf], acc[rf][cf], 0, 0, 0);
        PRIO0();
    };
    auto mfma1 = [&]{
        PRIO1();
        #pragma unroll
        for (int rf = 0; rf < 4; ++rf)
            #pragma unroll
            for (int cf = 0; cf < 2; ++cf)
                acc[rf][cf] = __builtin_amdgcn_mfma_f32_32x32x16_bf16(
                    aq1[rf], bq1[cf], acc[rf][cf], 0, 0, 0);
        PRIO0();
    };

    // prologue: stage tiles 0,1; tile 0 ready; prime set0 with (0,ks0)
    stageAB(0); stageAB(1);
    VMWAIT(4);
    RBAR();
    read0(0);

    #pragma unroll 2
    for (int t = 0; t < NKT - 2; ++t){
        stageAB(t + 2);          // 4 loads -> buf[(t+2)&3], lands ~2 tiles on
        read1(t);                // 6 ds_reads fly under mfma0
        mfma0();
        VMWAIT(4);               // tile t+1 landed (t+2 still flying)
        RBAR();
        read0(t + 1);            // 6 ds_reads fly under mfma1
        mfma1();
    }
    // t = NKT-2: no more stages; tile NKT-1 needs full drain
    read1(NKT - 2);
    mfma0();
    VMWAIT(0);
    RBAR();
    read0(NKT - 1);
    mfma1();
    // t = NKT-1
    read1(NKT - 1);
    mfma0();
    mfma1();

    // ---- epilogue: cross-wc row-max reduce, 1 atomicMax/row, collect ----
    __syncthreads();
    #pragma unroll
    for (int rf = 0; rf < 4; ++rf)
        #pragma unroll
        for (int q = 0; q < 16; ++q){
            float v = fmaxf(acc[rf][0][q], acc[rf][1][q]);
            v = fmaxf(v, __shfl_xor(v, 1));
            v = fmaxf(v, __shfl_xor(v, 2));
            v = fmaxf(v, __shfl_xor(v, 4));
            v = fmaxf(v, __shfl_xor(v, 8));
            v = fmaxf(v, __shfl_xor(v, 16));
            if (lm == 0){
                int row = wr * 128 + rf * 32 + (q & 3) + 8 * (q >> 2) + 4 * lh;
                sm.ep.redmax[row][wc] = v;
            }
        }
    __syncthreads();
    if (tid < 256){
        float m = fmaxf(fmaxf(sm.ep.redmax[tid][0], sm.ep.redmax[tid][1]),
                        fmaxf(sm.ep.redmax[tid][2], sm.ep.redmax[tid][3]));
        unsigned old = atomicMax(&rowMaxBits[mt * 256 + tid], encf(m));
        sm.ep.ths[tid] = fmaxf(m, decf(old)) - DELTA;
    }
    __syncthreads();
    #pragma unroll
    for (int rf = 0; rf < 4; ++rf)
        #pragma unroll
        for (int q = 0; q < 16; ++q){
            int row = wr * 128 + rf * 32 + (q & 3) + 8 * (q >> 2) + 4 * lh;
            float thr = sm.ep.ths[row];
            #pragma unroll
            for (int cf = 0; cf < 2; ++cf){
                if (acc[rf][cf][q] >= thr){
                    int gcol = nt * 256 + wc * 64 + cf * 32 + lm;
                    if (gcol < NTRAIN){
                        int grow = mt * 256 + row;
                        int slot = atomicAdd(&counts[grow], 1);
                        if (slot < CAP) cands[(size_t)grow * CAP + slot] = gcol;
                    }
                }
            }
        }
}

// ---- fallback GEMM (round-0 path, used only if ws too small) ----
__launch_bounds__(256)
__global__ void gemm_collect_kernel(const float* __restrict__ Aq,
                                    const float* __restrict__ Bt,
                                    unsigned* __restrict__ rowMaxBits,
                                    int* __restrict__ counts,
                                    int* __restrict__ cands){
    const int m0 = blockIdx.x * 128;
    const int n0 = blockIdx.y * 128;
    const int tid  = threadIdx.x;
    const int lane = tid & 63;
    const int wave = tid >> 6;
    const int wm = (wave >> 1) * 64;
    const int wn = (wave & 1) * 64;

    __shared__ union {
        struct { ushort As[128][32]; ushort Bs[128][32]; } s;
        float Csh[64][129];
    } sm;

    f32x4 acc[4][4];
    #pragma unroll
    for (int i = 0; i < 4; ++i)
        #pragma unroll
        for (int j = 0; j < 4; ++j)
            acc[i][j] = (f32x4){0.f, 0.f, 0.f, 0.f};

    const int fr = lane & 15;
    const int fg = lane >> 4;

    for (int kt = 0; kt < KDIM / 32; ++kt){
        const int k0 = kt * 32;
        __syncthreads();
        #pragma unroll
        for (int i = 0; i < 4; ++i){
            int f  = tid + i * 256;
            int r  = f >> 3;
            int kc = (f & 7) * 4;
            float4 av = *reinterpret_cast<const float4*>(Aq + (size_t)(m0 + r) * KDIM + k0 + kc);
            ushort4 ah; ah.x = cvt_bf16(av.x); ah.y = cvt_bf16(av.y);
            ah.z = cvt_bf16(av.z); ah.w = cvt_bf16(av.w);
            *reinterpret_cast<ushort4*>(&sm.s.As[r][kc]) = ah;
            int nr = n0 + r;
            float4 bv = make_float4(0.f, 0.f, 0.f, 0.f);
            if (nr < NTRAIN)
                bv = *reinterpret_cast<const float4*>(Bt + (size_t)nr * KDIM + k0 + kc);
            ushort4 bh; bh.x = cvt_bf16(bv.x); bh.y = cvt_bf16(bv.y);
            bh.z = cvt_bf16(bv.z); bh.w = cvt_bf16(bv.w);
            *reinterpret_cast<ushort4*>(&sm.s.Bs[r][kc]) = bh;
        }
        __syncthreads();
        s16x8 af[4], bfv[4];
        #pragma unroll
        for (int i = 0; i < 4; ++i){
            af[i]  = *reinterpret_cast<const s16x8*>(&sm.s.As[wm + i * 16 + fr][fg * 8]);
            bfv[i] = *reinterpret_cast<const s16x8*>(&sm.s.Bs[wn + i * 16 + fr][fg * 8]);
        }
        #pragma unroll
        for (int i = 0; i < 4; ++i)
            #pragma unroll
            for (int j = 0; j < 4; ++j)
                acc[i][j] = __builtin_amdgcn_mfma_f32_16x16x32_bf16(af[i], bfv[j], acc[i][j], 0, 0, 0);
    }

    for (int half = 0; half < 2; ++half){
        __syncthreads();
        if ((wave >> 1) == half){
            #pragma unroll
            for (int i = 0; i < 4; ++i)
                #pragma unroll
                for (int j = 0; j < 4; ++j)
                    #pragma unroll
                    for (int q = 0; q < 4; ++q){
                        int rr = i * 16 + (lane >> 4) * 4 + q;
                        int cc = wn + j * 16 + (lane & 15);
                        sm.Csh[rr][cc] = acc[i][j][q];
                    }
        }
        __syncthreads();
        if (tid < 64){
            int grow = m0 + half * 64 + tid;
            float mx = -1e30f;
            #pragma unroll 4
            for (int c = 0; c < 128; ++c) mx = fmaxf(mx, sm.Csh[tid][c]);
            unsigned old = atomicMax(&rowMaxBits[grow], encf(mx));
            float gmax = fmaxf(mx, decf(old));
            float thr = gmax - DELTA;
            for (int c = 0; c < 128; ++c){
                int gcol = n0 + c;
                if (gcol < NTRAIN && sm.Csh[tid][c] >= thr){
                    int slot = atomicAdd(&counts[grow], 1);
                    if (slot < CAP) cands[(size_t)grow * CAP + slot] = gcol;
                }
            }
        }
    }
}

// one block per query row: exact fp32 rescore, top-KSEL, softmax, output.
__launch_bounds__(256)
__global__ void rescore_output_kernel(const float* __restrict__ Aq,
                                      const float* __restrict__ Bt,
                                      const int* __restrict__ labels,
                                      const int* __restrict__ counts,
                                      const int* __restrict__ cands,
                                      float* __restrict__ out){
    const int row  = blockIdx.x;
    const int tid  = threadIdx.x;
    const int lane = tid & 63;
    const int wave = tid >> 6;

    __shared__ float q[KDIM];
    __shared__ float sv[CAP];
    __shared__ float rv[256];
    __shared__ int   ri[256];
    __shared__ float topS[KSEL];
    __shared__ int   topI[KSEL];
    __shared__ float cls[3][NCLS];

    for (int k = tid; k < KDIM; k += 256) q[k] = Aq[(size_t)row * KDIM + k];
    int m = counts[row]; if (m > CAP) m = CAP;
    __syncthreads();

    for (int c = wave; c < m; c += 4){
        int idx = cands[(size_t)row * CAP + c];
        const float* b = Bt + (size_t)idx * KDIM;
        float s = 0.f;
        #pragma unroll
        for (int u = 0; u < 12; ++u){
            int k = lane * 12 + u;
            s += q[k] * b[k];
        }
        #pragma unroll
        for (int off = 32; off; off >>= 1) s += __shfl_down(s, off);
        if (lane == 0) sv[c] = s;
    }
    __syncthreads();

    int msel = m < KSEL ? m : KSEL;
    for (int j = 0; j < msel; ++j){
        float bs = -1e30f; int bi = 0x7FFFFFFF;
        for (int c = tid; c < m; c += 256){
            float v = sv[c];
            if (v > bs){ bs = v; bi = c; }
        }
        rv[tid] = bs; ri[tid] = bi;
        __syncthreads();
        for (int st = 128; st; st >>= 1){
            if (tid < st){
                if (rv[tid + st] > rv[tid] ||
                    (rv[tid + st] == rv[tid] && ri[tid + st] < ri[tid])){
                    rv[tid] = rv[tid + st]; ri[tid] = ri[tid + st];
                }
            }
            __syncthreads();
        }
        if (tid == 0){
            topS[j] = rv[0];
            topI[j] = cands[(size_t)row * CAP + ri[0]];
            sv[ri[0]] = -1e30f;
        }
        __syncthreads();
    }

    for (int i = tid; i < 3 * NCLS; i += 256) (&cls[0][0])[i] = 0.f;
    __syncthreads();

    if (tid == 0){
        float s0 = topS[0];
        float e[KSEL];
        float Z = 0.f;
        for (int j = 0; j < msel; ++j){ e[j] = __expf((topS[j] - s0) * TINV); Z += e[j]; }
        float inv = 1.f / Z;
        for (int j = 0; j < msel; ++j){
            int lb = labels[topI[j]];
            float w = e[j] * inv;
            if (j < 10) cls[0][lb] += w;
            if (j < 50) cls[1][lb] += w;
            cls[2][lb] += w;
        }
    }
    __syncthreads();

    for (int c = tid; c < NCLS; c += 256){
        out[(size_t)row * NCLS + c]                         = cls[0][c];
        out[(size_t)MQ * NCLS + (size_t)row * NCLS + c]     = cls[1][c];
        out[(size_t)2 * MQ * NCLS + (size_t)row * NCLS + c] = cls[2][c];
    }
}

extern "C" void kernel_launch(void* const* d_in, const int* in_sizes, int n_in,
                              void* d_out, int out_size, void* d_ws, size_t ws_size,
                              hipStream_t stream){
    const float* Aq     = (const float*)d_in[0];
    const float* Bt     = (const float*)d_in[1];
    const int*   labels = (const int*)d_in[2];
    float* out = (float*)d_out;

    char* ws = (char*)d_ws;
    unsigned* rowMaxBits = (unsigned*)ws;                         // MQ u32
    int*      counts     = (int*)(ws + (size_t)MQ * 4);           // MQ i32
    int*      cands      = (int*)(ws + (size_t)MQ * 8);           // MQ*CAP i32
    ushort*   Abf        = (ushort*)(ws + (size_t)MQ * 8 + (size_t)MQ * CAP * 4);
    ushort*   Bbf        = Abf + (size_t)4 * NKT * 8192;

    const size_t need = (size_t)MQ * 8 + (size_t)MQ * CAP * 4
                      + ((size_t)4 * NKT * 8192 + (size_t)NT256 * NKT * 8192) * 2;

    hipLaunchKernelGGL(init_kernel, dim3(4), dim3(256), 0, stream, rowMaxBits, counts);

    if (ws_size >= need){
        hipLaunchKernelGGL(convert_tile_kernel, dim3((4 + NT256) * NKT), dim3(256), 0, stream,
                           Aq, Bt, Abf, Bbf);
        hipLaunchKernelGGL(gemm_fast_kernel, dim3(8 * 391), dim3(512), 0, stream,
                           Abf, Bbf, rowMaxBits, counts, cands);
    } else {
        hipLaunchKernelGGL(gemm_collect_kernel, dim3(8, (NTRAIN + 127) / 128), dim3(256), 0, stream,
                           Aq, Bt, rowMaxBits, counts, cands);
    }
    hipLaunchKernelGGL(rescore_output_kernel, dim3(MQ), dim3(256), 0, stream,
                       Aq, Bt, labels, counts, cands, out);
}

// Round 9
// 724.689 us; speedup vs baseline: 4.1917x; 1.0136x over previous
//
#include <hip/hip_runtime.h>
#include <hip/hip_bf16.h>
#include <math.h>

#define MQ      1024
#define NTRAIN  200000
#define NT256   782             // N-tiles of 256
#define KDIM    768
#define NKT     24              // K-panels of 32
#define NCLS    1000
#define CAP     1024
#define DELTA   8.0f
#define KSEL    32
#define TINV    (1.0f/0.07f)

typedef short s16x8  __attribute__((ext_vector_type(8)));
typedef float f32x4  __attribute__((ext_vector_type(4)));
typedef float f32x16 __attribute__((ext_vector_type(16)));

__device__ __forceinline__ unsigned encf(float x){
    unsigned u = __float_as_uint(x);
    return (u & 0x80000000u) ? ~u : (u | 0x80000000u);
}
__device__ __forceinline__ float decf(unsigned e){
    unsigned u = (e & 0x80000000u) ? (e & 0x7FFFFFFFu) : ~e;
    return __uint_as_float(u);
}
__device__ __forceinline__ ushort cvt_bf16(float x){
    unsigned u = __float_as_uint(x);
    u += 0x7FFFu + ((u >> 16) & 1u);   // round-to-nearest-even
    return (ushort)(u >> 16);
}
__device__ __forceinline__ void gload_lds16(const void* g, void* l){
    __builtin_amdgcn_global_load_lds(
        (const __attribute__((address_space(1))) unsigned int*)g,
        (__attribute__((address_space(3))) unsigned int*)l, 16, 0, 0);
}

#define VMWAIT(N) asm volatile("s_waitcnt vmcnt(" #N ")" ::: "memory")
#define RBAR()    asm volatile("s_barrier" ::: "memory")
#define PRIO1()   __builtin_amdgcn_s_setprio(1)
#define PRIO0()   __builtin_amdgcn_s_setprio(0)

__global__ void init_kernel(unsigned* rowMaxBits, int* counts){
    int i = blockIdx.x * blockDim.x + threadIdx.x;
    if (i < MQ){ rowMaxBits[i] = 0u; counts[i] = 0; }
}

// fp32 -> bf16 into 32x32x16-FRAGMENT-TILED layout.
// Panel = 256 rows x 32 k; chunk(r,k) = ((r>>5)*2 + (k>>4))*64 + (r&31)
// + 32*((k>>3)&1), byte j = k&7.  A wave's fragment ds_read = 64 consecutive
// chunks (1 KB) -> zero conflicts; staging is a pure linear copy.
__launch_bounds__(256)
__global__ void convert_tile_kernel(const float* __restrict__ Aq,
                                    const float* __restrict__ Bt,
                                    ushort* __restrict__ Abf,
                                    ushort* __restrict__ Bbf){
    const int bid = blockIdx.x;            // (4 + 782) * 24 panels
    const int rt  = bid / NKT;
    const int kt  = bid - rt * NKT;
    const int tid = threadIdx.x;

    const float* src; ushort* dst; int rowBase, nRows;
    if (rt < 4){
        src = Aq; dst = Abf + (size_t)bid * 8192;
        rowBase = rt * 256; nRows = MQ;
    } else {
        src = Bt; dst = Bbf + (size_t)((rt - 4) * NKT + kt) * 8192;
        rowBase = (rt - 4) * 256; nRows = NTRAIN;
    }

    __shared__ ushort tile[8192];   // 16 KB

    #pragma unroll
    for (int i = 0; i < 8; ++i){
        int idx = i * 256 + tid;           // float4 unit, 0..2047
        int r   = idx >> 3;                // 0..255
        int c4  = idx & 7;                 // float4 col within 32-k
        int grow = rowBase + r;
        float4 v = make_float4(0.f, 0.f, 0.f, 0.f);
        if (grow < nRows)
            v = *reinterpret_cast<const float4*>(src + (size_t)grow * KDIM + kt * 32 + c4 * 4);
        ushort4 h; h.x = cvt_bf16(v.x); h.y = cvt_bf16(v.y);
        h.z = cvt_bf16(v.z); h.w = cvt_bf16(v.w);
        int k = c4 * 4;
        int chunk = ((r >> 5) * 2 + (k >> 4)) * 64 + (r & 31) + 32 * ((k >> 3) & 1);
        *reinterpret_cast<ushort4*>(&tile[chunk * 8 + (k & 7)]) = h;
    }
    __syncthreads();
    #pragma unroll
    for (int i = 0; i < 4; ++i){
        int c = i * 256 + tid;             // chunk id 0..1023
        *reinterpret_cast<s16x8*>(dst + (size_t)c * 8) =
            *reinterpret_cast<const s16x8*>(&tile[c * 8]);
    }
}

// 256x256 tile, 8 waves, 32x32x16 MFMA, m201-style PHASE schedule:
// iteration = 2 K-panels, 4 phases; each phase {6 ds_read | stage one
// 16KB panel-half (2 gload_lds) | counted VMWAIT(4) at phases 2,4 |
// s_barrier | sched_barrier | setprio(1) 8 MFMA setprio(0) | s_barrier}.
// Steady state: panel staged 2-3 phases before its drain; vmcnt never 0
// until the peeled tail. 4 LDS panel-buffers (128 KB).
__launch_bounds__(512, 2)
__global__ void gemm_fast_kernel(const ushort* __restrict__ Abf,
                                 const ushort* __restrict__ Bbf,
                                 unsigned* __restrict__ rowMaxBits,
                                 int* __restrict__ counts,
                                 int* __restrict__ cands){
    const int g    = blockIdx.x;                 // 3128 = 8 * 391
    const int wgid = (g & 7) * 391 + (g >> 3);   // bijective XCD chunking
    const int mt   = wgid & 3;
    const int nt   = wgid >> 2;
    const int tid  = threadIdx.x;
    const int lane = tid & 63;
    const int wave = tid >> 6;
    const int wr   = wave >> 2;      // 0..1  rows wr*128
    const int wc   = wave & 3;       // 0..3  cols wc*64
    const int lh   = lane >> 5;
    const int lm   = lane & 31;

    __shared__ union {
        ushort stg[4][2][8192];                       // 128 KB staging
        struct { float redmax[256][4]; float ths[256]; } ep;
    } sm;

    const ushort* Apan = Abf + (size_t)mt * NKT * 8192;
    const ushort* Bpan = Bbf + (size_t)nt * NKT * 8192;

    f32x16 acc[4][2];
    #pragma unroll
    for (int i = 0; i < 4; ++i)
        #pragma unroll
        for (int j = 0; j < 2; ++j)
            #pragma unroll
            for (int q = 0; q < 16; ++q)
                acc[i][j][q] = 0.f;

    s16x8 aq[4], bq[2];

    auto stageA = [&](int p){
        const ushort* s = Apan + (size_t)p * 8192;
        ushort* d = &sm.stg[p & 3][0][0];
        gload_lds16(s + (size_t)tid * 8,          d + (size_t)tid * 8);
        gload_lds16(s + (size_t)(512 + tid) * 8,  d + (size_t)(512 + tid) * 8);
    };
    auto stageB = [&](int p){
        const ushort* s = Bpan + (size_t)p * 8192;
        ushort* d = &sm.stg[p & 3][1][0];
        gload_lds16(s + (size_t)tid * 8,          d + (size_t)tid * 8);
        gload_lds16(s + (size_t)(512 + tid) * 8,  d + (size_t)(512 + tid) * 8);
    };
    auto readP = [&](int p, int ks){
        const ushort* As = &sm.stg[p & 3][0][0];
        const ushort* Bs = &sm.stg[p & 3][1][0];
        #pragma unroll
        for (int cf = 0; cf < 2; ++cf)
            bq[cf] = *reinterpret_cast<const s16x8*>(
                &Bs[(((wc * 2 + cf) * 2 + ks) * 64 + lane) * 8]);
        #pragma unroll
        for (int rf = 0; rf < 4; ++rf)
            aq[rf] = *reinterpret_cast<const s16x8*>(
                &As[(((wr * 4 + rf) * 2 + ks) * 64 + lane) * 8]);
    };
    auto mfmaC = [&]{
        PRIO1();
        #pragma unroll
        for (int rf = 0; rf < 4; ++rf)
            #pragma unroll
            for (int cf = 0; cf < 2; ++cf)
                acc[rf][cf] = __builtin_amdgcn_mfma_f32_32x32x16_bf16(
                    aq[rf], bq[cf], acc[rf][cf], 0, 0, 0);
        PRIO0();
    };

#define PHASE(P, KS, STAGE, WAIT) { \
    readP(P, KS); \
    STAGE; \
    WAIT; \
    RBAR(); \
    __builtin_amdgcn_sched_barrier(0); \
    mfmaC(); \
    RBAR(); }

    // prologue: panels 0,1 fully staged and drained
    stageA(0); stageB(0); stageA(1); stageB(1);
    VMWAIT(0);
    RBAR();

    // main loop: 11 iterations x 4 phases; stages panels 2..23
    #pragma unroll 2
    for (int t = 0; t < 21; t += 2){
        PHASE(t,     0, stageA(t + 2), (void)0);
        PHASE(t,     1, stageB(t + 2), VMWAIT(4));
        PHASE(t + 1, 0, stageA(t + 3), (void)0);
        PHASE(t + 1, 1, stageB(t + 3), VMWAIT(4));
    }
    // peeled tail: panels 22,23 (no staging; drain remaining loads)
    PHASE(22, 0, (void)0, (void)0);
    PHASE(22, 1, (void)0, VMWAIT(0));
    PHASE(23, 0, (void)0, (void)0);
    readP(23, 1);
    mfmaC();
#undef PHASE

    // ---- epilogue: cross-wc row-max reduce, 1 atomicMax/row, collect ----
    __syncthreads();
    #pragma unroll
    for (int rf = 0; rf < 4; ++rf)
        #pragma unroll
        for (int q = 0; q < 16; ++q){
            float v = fmaxf(acc[rf][0][q], acc[rf][1][q]);
            v = fmaxf(v, __shfl_xor(v, 1));
            v = fmaxf(v, __shfl_xor(v, 2));
            v = fmaxf(v, __shfl_xor(v, 4));
            v = fmaxf(v, __shfl_xor(v, 8));
            v = fmaxf(v, __shfl_xor(v, 16));
            if (lm == 0){
                int row = wr * 128 + rf * 32 + (q & 3) + 8 * (q >> 2) + 4 * lh;
                sm.ep.redmax[row][wc] = v;
            }
        }
    __syncthreads();
    if (tid < 256){
        float m = fmaxf(fmaxf(sm.ep.redmax[tid][0], sm.ep.redmax[tid][1]),
                        fmaxf(sm.ep.redmax[tid][2], sm.ep.redmax[tid][3]));
        unsigned old = atomicMax(&rowMaxBits[mt * 256 + tid], encf(m));
        sm.ep.ths[tid] = fmaxf(m, decf(old)) - DELTA;
    }
    __syncthreads();
    #pragma unroll
    for (int rf = 0; rf < 4; ++rf)
        #pragma unroll
        for (int q = 0; q < 16; ++q){
            int row = wr * 128 + rf * 32 + (q & 3) + 8 * (q >> 2) + 4 * lh;
            float thr = sm.ep.ths[row];
            #pragma unroll
            for (int cf = 0; cf < 2; ++cf){
                if (acc[rf][cf][q] >= thr){
                    int gcol = nt * 256 + wc * 64 + cf * 32 + lm;
                    if (gcol < NTRAIN){
                        int grow = mt * 256 + row;
                        int slot = atomicAdd(&counts[grow], 1);
                        if (slot < CAP) cands[(size_t)grow * CAP + slot] = gcol;
                    }
                }
            }
        }
}

// ---- fallback GEMM (round-0 path, used only if ws too small) ----
__launch_bounds__(256)
__global__ void gemm_collect_kernel(const float* __restrict__ Aq,
                                    const float* __restrict__ Bt,
                                    unsigned* __restrict__ rowMaxBits,
                                    int* __restrict__ counts,
                                    int* __restrict__ cands){
    const int m0 = blockIdx.x * 128;
    const int n0 = blockIdx.y * 128;
    const int tid  = threadIdx.x;
    const int lane = tid & 63;
    const int wave = tid >> 6;
    const int wm = (wave >> 1) * 64;
    const int wn = (wave & 1) * 64;

    __shared__ union {
        struct { ushort As[128][32]; ushort Bs[128][32]; } s;
        float Csh[64][129];
    } sm;

    f32x4 acc[4][4];
    #pragma unroll
    for (int i = 0; i < 4; ++i)
        #pragma unroll
        for (int j = 0; j < 4; ++j)
            acc[i][j] = (f32x4){0.f, 0.f, 0.f, 0.f};

    const int fr = lane & 15;
    const int fg = lane >> 4;

    for (int kt = 0; kt < KDIM / 32; ++kt){
        const int k0 = kt * 32;
        __syncthreads();
        #pragma unroll
        for (int i = 0; i < 4; ++i){
            int f  = tid + i * 256;
            int r  = f >> 3;
            int kc = (f & 7) * 4;
            float4 av = *reinterpret_cast<const float4*>(Aq + (size_t)(m0 + r) * KDIM + k0 + kc);
            ushort4 ah; ah.x = cvt_bf16(av.x); ah.y = cvt_bf16(av.y);
            ah.z = cvt_bf16(av.z); ah.w = cvt_bf16(av.w);
            *reinterpret_cast<ushort4*>(&sm.s.As[r][kc]) = ah;
            int nr = n0 + r;
            float4 bv = make_float4(0.f, 0.f, 0.f, 0.f);
            if (nr < NTRAIN)
                bv = *reinterpret_cast<const float4*>(Bt + (size_t)nr * KDIM + k0 + kc);
            ushort4 bh; bh.x = cvt_bf16(bv.x); bh.y = cvt_bf16(bv.y);
            bh.z = cvt_bf16(bv.z); bh.w = cvt_bf16(bv.w);
            *reinterpret_cast<ushort4*>(&sm.s.Bs[r][kc]) = bh;
        }
        __syncthreads();
        s16x8 af[4], bfv[4];
        #pragma unroll
        for (int i = 0; i < 4; ++i){
            af[i]  = *reinterpret_cast<const s16x8*>(&sm.s.As[wm + i * 16 + fr][fg * 8]);
            bfv[i] = *reinterpret_cast<const s16x8*>(&sm.s.Bs[wn + i * 16 + fr][fg * 8]);
        }
        #pragma unroll
        for (int i = 0; i < 4; ++i)
            #pragma unroll
            for (int j = 0; j < 4; ++j)
                acc[i][j] = __builtin_amdgcn_mfma_f32_16x16x32_bf16(af[i], bfv[j], acc[i][j], 0, 0, 0);
    }

    for (int half = 0; half < 2; ++half){
        __syncthreads();
        if ((wave >> 1) == half){
            #pragma unroll
            for (int i = 0; i < 4; ++i)
                #pragma unroll
                for (int j = 0; j < 4; ++j)
                    #pragma unroll
                    for (int q = 0; q < 4; ++q){
                        int rr = i * 16 + (lane >> 4) * 4 + q;
                        int cc = wn + j * 16 + (lane & 15);
                        sm.Csh[rr][cc] = acc[i][j][q];
                    }
        }
        __syncthreads();
        if (tid < 64){
            int grow = m0 + half * 64 + tid;
            float mx = -1e30f;
            #pragma unroll 4
            for (int c = 0; c < 128; ++c) mx = fmaxf(mx, sm.Csh[tid][c]);
            unsigned old = atomicMax(&rowMaxBits[grow], encf(mx));
            float gmax = fmaxf(mx, decf(old));
            float thr = gmax - DELTA;
            for (int c = 0; c < 128; ++c){
                int gcol = n0 + c;
                if (gcol < NTRAIN && sm.Csh[tid][c] >= thr){
                    int slot = atomicAdd(&counts[grow], 1);
                    if (slot < CAP) cands[(size_t)grow * CAP + slot] = gcol;
                }
            }
        }
    }
}

// one block per query row: exact fp32 rescore, top-KSEL, softmax, output.
__launch_bounds__(256)
__global__ void rescore_output_kernel(const float* __restrict__ Aq,
                                      const float* __restrict__ Bt,
                                      const int* __restrict__ labels,
                                      const int* __restrict__ counts,
                                      const int* __restrict__ cands,
                                      float* __restrict__ out){
    const int row  = blockIdx.x;
    const int tid  = threadIdx.x;
    const int lane = tid & 63;
    const int wave = tid >> 6;

    __shared__ float q[KDIM];
    __shared__ float sv[CAP];
    __shared__ float rv[256];
    __shared__ int   ri[256];
    __shared__ float topS[KSEL];
    __shared__ int   topI[KSEL];
    __shared__ float cls[3][NCLS];

    for (int k = tid; k < KDIM; k += 256) q[k] = Aq[(size_t)row * KDIM + k];
    int m = counts[row]; if (m > CAP) m = CAP;
    __syncthreads();

    for (int c = wave; c < m; c += 4){
        int idx = cands[(size_t)row * CAP + c];
        const float* b = Bt + (size_t)idx * KDIM;
        float s = 0.f;
        #pragma unroll
        for (int u = 0; u < 12; ++u){
            int k = lane * 12 + u;
            s += q[k] * b[k];
        }
        #pragma unroll
        for (int off = 32; off; off >>= 1) s += __shfl_down(s, off);
        if (lane == 0) sv[c] = s;
    }
    __syncthreads();

    int msel = m < KSEL ? m : KSEL;
    for (int j = 0; j < msel; ++j){
        float bs = -1e30f; int bi = 0x7FFFFFFF;
        for (int c = tid; c < m; c += 256){
            float v = sv[c];
            if (v > bs){ bs = v; bi = c; }
        }
        rv[tid] = bs; ri[tid] = bi;
        __syncthreads();
        for (int st = 128; st; st >>= 1){
            if (tid < st){
                if (rv[tid + st] > rv[tid] ||
                    (rv[tid + st] == rv[tid] && ri[tid + st] < ri[tid])){
                    rv[tid] = rv[tid + st]; ri[tid] = ri[tid + st];
                }
            }
            __syncthreads();
        }
        if (tid == 0){
            topS[j] = rv[0];
            topI[j] = cands[(size_t)row * CAP + ri[0]];
            sv[ri[0]] = -1e30f;
        }
        __syncthreads();
    }

    for (int i = tid; i < 3 * NCLS; i += 256) (&cls[0][0])[i] = 0.f;
    __syncthreads();

    if (tid == 0){
        float s0 = topS[0];
        float e[KSEL];
        float Z = 0.f;
        for (int j = 0; j < msel; ++j){ e[j] = __expf((topS[j] - s0) * TINV); Z += e[j]; }
        float inv = 1.f / Z;
        for (int j = 0; j < msel; ++j){
            int lb = labels[topI[j]];
            float w = e[j] * inv;
            if (j < 10) cls[0][lb] += w;
            if (j < 50) cls[1][lb] += w;
            cls[2][lb] += w;
        }
    }
    __syncthreads();

    for (int c = tid; c < NCLS; c += 256){
        out[(size_t)row * NCLS + c]                         = cls[0][c];
        out[(size_t)MQ * NCLS + (size_t)row * NCLS + c]     = cls[1][c];
        out[(size_t)2 * MQ * NCLS + (size_t)row * NCLS + c] = cls[2][c];
    }
}

extern "C" void kernel_launch(void* const* d_in, const int* in_sizes, int n_in,
                              void* d_out, int out_size, void* d_ws, size_t ws_size,
                              hipStream_t stream){
    const float* Aq     = (const float*)d_in[0];
    const float* Bt     = (const float*)d_in[1];
    const int*   labels = (const int*)d_in[2];
    float* out = (float*)d_out;

    char* ws = (char*)d_ws;
    unsigned* rowMaxBits = (unsigned*)ws;                         // MQ u32
    int*      counts     = (int*)(ws + (size_t)MQ * 4);           // MQ i32
    int*      cands      = (int*)(ws + (size_t)MQ * 8);           // MQ*CAP i32
    ushort*   Abf        = (ushort*)(ws + (size_t)MQ * 8 + (size_t)MQ * CAP * 4);
    ushort*   Bbf        = Abf + (size_t)4 * NKT * 8192;

    const size_t need = (size_t)MQ * 8 + (size_t)MQ * CAP * 4
                      + ((size_t)4 * NKT * 8192 + (size_t)NT256 * NKT * 8192) * 2;

    hipLaunchKernelGGL(init_kernel, dim3(4), dim3(256), 0, stream, rowMaxBits, counts);

    if (ws_size >= need){
        hipLaunchKernelGGL(convert_tile_kernel, dim3((4 + NT256) * NKT), dim3(256), 0, stream,
                           Aq, Bt, Abf, Bbf);
        hipLaunchKernelGGL(gemm_fast_kernel, dim3(8 * 391), dim3(512), 0, stream,
                           Abf, Bbf, rowMaxBits, counts, cands);
    } else {
        hipLaunchKernelGGL(gemm_collect_kernel, dim3(8, (NTRAIN + 127) / 128), dim3(256), 0, stream,
                           Aq, Bt, rowMaxBits, counts, cands);
    }
    hipLaunchKernelGGL(rescore_output_kernel, dim3(MQ), dim3(256), 0, stream,
                       Aq, Bt, labels, counts, cands, out);
}